// Round 8
// baseline (225.324 us; speedup 1.0000x reference)
//
#include <hip/hip_runtime.h>
#include <hip/hip_bf16.h>

#define S_LEN 4096
#define NH 4
#define HD 256
#define WIN 512
#define ATT_SCALE 0.0625f   // 256^-0.5
#define QKV_N 1536          // packed q(1024) | k(256) | v(256)

typedef short s16x8 __attribute__((ext_vector_type(8)));
typedef float f32x4 __attribute__((ext_vector_type(4)));

static __device__ inline unsigned short f2bf(float f) {
  union { float f; unsigned int u; } v; v.f = f;
  unsigned int r = v.u + 0x7fff + ((v.u >> 16) & 1);   // RNE
  return (unsigned short)(r >> 16);
}
static __device__ inline float bf2f(unsigned short h) {
  union { unsigned int u; float f; } v; v.u = ((unsigned int)h) << 16;
  return v.f;
}
static __device__ inline void gl2lds16(const void* g, void* l) {
  __builtin_amdgcn_global_load_lds(
      (const __attribute__((address_space(1))) unsigned int*)g,
      (__attribute__((address_space(3))) unsigned int*)l, 16, 0, 0);
}

// ---------------------------------------------------------------------------
// Fused prep: region [0,5120) = x fp32->bf16 cast; then 4 transpose+cast
// weight regions (Wq,Wk,Wv -> packed Wqkvt; Wo -> Wot). One dispatch.
// ---------------------------------------------------------------------------
static __device__ void trcast_tile(const float* __restrict__ src,
                                   unsigned short* __restrict__ dst,
                                   int K, int N, int bn, int bk, int tid,
                                   float* ts /*[64][65]*/) {
#pragma unroll
  for (int it = 0; it < 4; ++it) {
    const int c = it * 256 + tid;
    const int row = c >> 4, col4 = (c & 15) << 2;
    const float4 v = *(const float4*)(src + (size_t)(bk * 64 + row) * N + bn * 64 + col4);
    ts[row * 65 + col4 + 0] = v.x; ts[row * 65 + col4 + 1] = v.y;
    ts[row * 65 + col4 + 2] = v.z; ts[row * 65 + col4 + 3] = v.w;
  }
  __syncthreads();
#pragma unroll
  for (int it = 0; it < 4; ++it) {
    const int c = it * 256 + tid;
    const int nrow = c >> 4, kc4 = (c & 15) << 2;
    const unsigned int p0 = f2bf(ts[(kc4 + 0) * 65 + nrow]) | ((unsigned int)f2bf(ts[(kc4 + 1) * 65 + nrow]) << 16);
    const unsigned int p1 = f2bf(ts[(kc4 + 2) * 65 + nrow]) | ((unsigned int)f2bf(ts[(kc4 + 3) * 65 + nrow]) << 16);
    *(uint2*)(dst + (size_t)(bn * 64 + nrow) * K + bk * 64 + kc4) = make_uint2(p0, p1);
  }
}

__global__ __launch_bounds__(256) void prep_kernel(
    const float* __restrict__ x, unsigned short* __restrict__ xb,
    const float* __restrict__ Wq, const float* __restrict__ Wk,
    const float* __restrict__ Wv, const float* __restrict__ Wo,
    unsigned short* __restrict__ Wqkvt, unsigned short* __restrict__ Wot) {
  __shared__ float ts[64 * 65];
  const int g = blockIdx.x;
  const int tid = threadIdx.x;
  if (g < 5120) {                    // cvt x -> bf16 (1310720 float4 elems)
    const int t = g * 256 + tid;
    const float4 v = ((const float4*)x)[t];
    const unsigned int p0 = f2bf(v.x) | ((unsigned int)f2bf(v.y) << 16);
    const unsigned int p1 = f2bf(v.z) | ((unsigned int)f2bf(v.w) << 16);
    *(uint2*)(xb + (size_t)t * 4) = make_uint2(p0, p1);
  } else if (g < 5280) {             // Wq: N=1024 (16), K=640 (10)
    const int g2 = g - 5120;
    trcast_tile(Wq, Wqkvt, 640, 1024, g2 & 15, g2 >> 4, tid, ts);
  } else if (g < 5320) {             // Wk: N=256 (4), K=640 (10)
    const int g2 = g - 5280;
    trcast_tile(Wk, Wqkvt + (size_t)1024 * 640, 640, 256, g2 & 3, g2 >> 2, tid, ts);
  } else if (g < 5360) {             // Wv
    const int g2 = g - 5320;
    trcast_tile(Wv, Wqkvt + (size_t)1280 * 640, 640, 256, g2 & 3, g2 >> 2, tid, ts);
  } else {                           // Wo: N=640 (10), K=1024 (16)
    const int g2 = g - 5360;
    trcast_tile(Wo, Wot, 1024, 640, g2 % 10, g2 / 10, tid, ts);
  }
}

// ---------------------------------------------------------------------------
// bf16 MFMA GEMM (m97 structure): C[M,N] = A[M,K] @ Bt[N,K]^T. 128x128 tile.
// ---------------------------------------------------------------------------
template <bool BF16OUT>
__global__ __launch_bounds__(256) void gemm_bt(const unsigned short* __restrict__ A,
                                               const unsigned short* __restrict__ Bt,
                                               void* __restrict__ Cv,
                                               int M, int N, int K) {
  __shared__ unsigned short As[128 * 32];
  __shared__ unsigned short Bs[128 * 32];
  const int tid = threadIdx.x;
  const int wave = tid >> 6, lane = tid & 63;
  const int ln15 = lane & 15, lgr = lane >> 4;
  const int bm = blockIdx.y, bn = blockIdx.x;
  const int wr = wave & 1, wc = wave >> 1;
  const unsigned short* Ab = A + (size_t)bm * 128 * K;
  const unsigned short* Bb = Bt + (size_t)bn * 128 * K;

  f32x4 acc[4][4];
#pragma unroll
  for (int mt = 0; mt < 4; ++mt)
#pragma unroll
    for (int nt = 0; nt < 4; ++nt) acc[mt][nt] = (f32x4){0.f, 0.f, 0.f, 0.f};

  for (int kt = 0; kt < K; kt += 32) {
#pragma unroll
    for (int i = 0; i < 2; ++i) {
      const int c = tid + 256 * i;
      const int row = c >> 2, kc = (c & 3) << 3;
      gl2lds16(Ab + (size_t)row * K + kt + kc, &As[c * 8]);
      gl2lds16(Bb + (size_t)row * K + kt + kc, &Bs[c * 8]);
    }
    __syncthreads();
    s16x8 af[4], bfr[4];
#pragma unroll
    for (int t = 0; t < 4; ++t) {
      af[t]  = *(const s16x8*)&As[(wr * 64 + t * 16 + ln15) * 32 + lgr * 8];
      bfr[t] = *(const s16x8*)&Bs[(wc * 64 + t * 16 + ln15) * 32 + lgr * 8];
    }
#pragma unroll
    for (int mt = 0; mt < 4; ++mt)
#pragma unroll
      for (int nt = 0; nt < 4; ++nt)
        acc[mt][nt] = __builtin_amdgcn_mfma_f32_16x16x32_bf16(af[mt], bfr[nt], acc[mt][nt], 0, 0, 0);
    __syncthreads();
  }

#pragma unroll
  for (int mt = 0; mt < 4; ++mt)
#pragma unroll
    for (int nt = 0; nt < 4; ++nt)
#pragma unroll
      for (int r = 0; r < 4; ++r) {
        const size_t row = bm * 128 + wr * 64 + mt * 16 + lgr * 4 + r;
        const size_t col = bn * 128 + wc * 64 + nt * 16 + ln15;
        if (BF16OUT) ((unsigned short*)Cv)[row * N + col] = f2bf(acc[mt][nt][r]);
        else         ((float*)Cv)[row * N + col] = acc[mt][nt][r];
      }
}

// ---------------------------------------------------------------------------
// 64x128-tile variant (fp32 out) for the output projection: N=640 -> 5 n-tiles,
// grid 128x5 = 640 blocks (2.5/CU vs 1.25/CU at 128x128 -> smaller tail).
// Wave wc owns 32 n-cols; acc 4x2 per wave.
// ---------------------------------------------------------------------------
__global__ __launch_bounds__(256) void gemm_bt64(const unsigned short* __restrict__ A,
                                                 const unsigned short* __restrict__ Bt,
                                                 float* __restrict__ C,
                                                 int M, int N, int K) {
  __shared__ unsigned short As[64 * 32];
  __shared__ unsigned short Bs[128 * 32];
  const int tid = threadIdx.x;
  const int wave = tid >> 6, lane = tid & 63;
  const int ln15 = lane & 15, lgr = lane >> 4;
  const int bm = blockIdx.y, bn = blockIdx.x;
  const unsigned short* Ab = A + (size_t)bm * 64 * K;
  const unsigned short* Bb = Bt + (size_t)bn * 128 * K;

  f32x4 acc[4][2];
#pragma unroll
  for (int mt = 0; mt < 4; ++mt)
#pragma unroll
    for (int nt = 0; nt < 2; ++nt) acc[mt][nt] = (f32x4){0.f, 0.f, 0.f, 0.f};

  for (int kt = 0; kt < K; kt += 32) {
    {
      const int row = tid >> 2, kc = (tid & 3) << 3;
      gl2lds16(Ab + (size_t)row * K + kt + kc, &As[tid * 8]);
#pragma unroll
      for (int i = 0; i < 2; ++i) {
        const int c = tid + 256 * i;
        const int brow = c >> 2, bkc = (c & 3) << 3;
        gl2lds16(Bb + (size_t)brow * K + kt + bkc, &Bs[c * 8]);
      }
    }
    __syncthreads();
    s16x8 af[4], bfr[2];
#pragma unroll
    for (int t = 0; t < 4; ++t)
      af[t] = *(const s16x8*)&As[(t * 16 + ln15) * 32 + lgr * 8];
#pragma unroll
    for (int t = 0; t < 2; ++t)
      bfr[t] = *(const s16x8*)&Bs[(wave * 32 + t * 16 + ln15) * 32 + lgr * 8];
#pragma unroll
    for (int mt = 0; mt < 4; ++mt)
#pragma unroll
      for (int nt = 0; nt < 2; ++nt)
        acc[mt][nt] = __builtin_amdgcn_mfma_f32_16x16x32_bf16(af[mt], bfr[nt], acc[mt][nt], 0, 0, 0);
    __syncthreads();
  }

#pragma unroll
  for (int mt = 0; mt < 4; ++mt)
#pragma unroll
    for (int nt = 0; nt < 2; ++nt)
#pragma unroll
      for (int r = 0; r < 4; ++r) {
        const size_t row = bm * 64 + mt * 16 + lgr * 4 + r;
        const size_t col = bn * 128 + wave * 32 + nt * 16 + ln15;
        C[row * N + col] = acc[mt][nt][r];
      }
}

// ---------------------------------------------------------------------------
// K-only RMSNorm+RoPE (blocks [0,2048)) + V-transpose (blocks [2048,2304)).
//
// Q rows are no longer processed here: each Q row is consumed by exactly ONE
// attn block (MQA), so Q norm+rope is fused into attn's Q-fragment load --
// saves the 21MB read + 21MB write round-trip for Q. K rows stay precomputed
// (each K row is re-read by ~36 attn blocks).
//
// Norm part wave-per-row: one wave = one 256-elem row, 4 elems/lane via uint2,
// wave-local shfl reduce, zero barriers/LDS.
//
// V-transpose (unchanged) uses INTERLEAVED key storage order
// s = 2*(jj&15) | (jj>>4), so attention's P round-trip can write packed b32
// pairs (PV is key-permutation invariant as long as P cols and Vt cols share
// the order).
// ---------------------------------------------------------------------------
__global__ __launch_bounds__(256) void normrope_vt_kernel(
    unsigned short* __restrict__ qkv,
    const float* __restrict__ cosb, const float* __restrict__ sinb,
    const float* __restrict__ kw,
    unsigned short* __restrict__ vtb) {
  const int bid = blockIdx.x;
  const int tid = threadIdx.x;
  if (bid < 2048) {
    const int lane = tid & 63, wave = tid >> 6;
    const int bs = bid * 4 + wave;           // 0..8191 (K row id)
    const int s = bs & (S_LEN - 1);
    unsigned short* row = qkv + (size_t)bs * QKV_N + 4 * HD;
    // lane handles elements [4*lane, 4*lane+4) = rope pairs pi=2*lane, 2*lane+1
    const uint2 pv = *(const uint2*)(row + 4 * lane);
    float xv[4];
    xv[0] = bf2f((unsigned short)(pv.x & 0xffff));
    xv[1] = bf2f((unsigned short)(pv.x >> 16));
    xv[2] = bf2f((unsigned short)(pv.y & 0xffff));
    xv[3] = bf2f((unsigned short)(pv.y >> 16));
    float ssq = xv[0] * xv[0] + xv[1] * xv[1] + xv[2] * xv[2] + xv[3] * xv[3];
#pragma unroll
    for (int off = 32; off > 0; off >>= 1) ssq += __shfl_xor(ssq, off);
    const float inv = rsqrtf(ssq * (1.0f / 256.0f) + 1e-6f);
    const float4 wv = *(const float4*)(kw + 4 * lane);
    const float2 cv = *(const float2*)(cosb + (size_t)s * (HD / 2) + 2 * lane);
    const float2 sv = *(const float2*)(sinb + (size_t)s * (HD / 2) + 2 * lane);
    const float a0 = xv[0] * inv * (1.0f + wv.x);
    const float b0 = xv[1] * inv * (1.0f + wv.y);
    const float a1 = xv[2] * inv * (1.0f + wv.z);
    const float b1 = xv[3] * inv * (1.0f + wv.w);
    const float o0 = a0 * cv.x - b0 * sv.x;
    const float o1 = a0 * sv.x + b0 * cv.x;
    const float o2 = a1 * cv.y - b1 * sv.y;
    const float o3 = a1 * sv.y + b1 * cv.y;
    uint2 ov;
    ov.x = (unsigned int)f2bf(o0) | ((unsigned int)f2bf(o1) << 16);
    ov.y = (unsigned int)f2bf(o2) | ((unsigned int)f2bf(o3) << 16);
    *(uint2*)(row + 4 * lane) = ov;
  } else {
    __shared__ unsigned short ts[32][264];
    const int g2 = bid - 2048;
    const int b = g2 >> 7, jt = g2 & 127;
    const unsigned short* src = qkv + ((size_t)(b * S_LEN) + jt * 32) * QKV_N + 5 * HD;
#pragma unroll
    for (int it = 0; it < 4; ++it) {
      const int c = tid + 256 * it;
      const int row = c >> 5, col8 = (c & 31) << 3;
      *(uint4*)&ts[row][col8] = *(const uint4*)(src + (size_t)row * QKV_N + col8);
    }
    __syncthreads();
    unsigned short tmp[32];
#pragma unroll
    for (int s2 = 0; s2 < 32; ++s2) {
      const int jj = (s2 >> 1) | ((s2 & 1) << 4);   // inverse of s = 2*(jj&15)|(jj>>4)
      tmp[s2] = ts[jj][tid];
    }
    unsigned short* dst = vtb + ((size_t)(b * 128 + jt) * 256 + tid) * 32;
#pragma unroll
    for (int wq = 0; wq < 4; ++wq) *(uint4*)(dst + wq * 8) = *(uint4*)(tmp + wq * 8);
  }
}

// ---------------------------------------------------------------------------
// Flash-style sliding-window MQA, bf16 MFMA — R0 loop structure (verified
// best) + FUSED Q RMSNorm+RoPE in the prologue.
//
// Q prep: each lane's 8 qfrag chunks cover cols f*32+lgr*8..+8 -> rope pairs
// are lane-local; full-row ssq via 2 shfl_xor (lgr spans the row). Runs once
// per block, amortized over ~19 K-tile iterations.
// ---------------------------------------------------------------------------
#define PS_LD 40

__global__ __launch_bounds__(256) void attn_mfma_kernel(
    const unsigned short* __restrict__ qkv, const unsigned short* __restrict__ vtb,
    unsigned short* __restrict__ aob,
    const float* __restrict__ cosb, const float* __restrict__ sinb,
    const float* __restrict__ qw) {
  const int g = blockIdx.x;
  const int xcd = g & 7, slot = g >> 3;      // assume block j -> XCD j%8
  const int h = slot >> 4;                   // 0..3
  const int qt = xcd * 16 + (slot & 15);     // 0..127
  const int b = qt >> 6;
  const int q0 = (qt & 63) << 6;
  const int tid = threadIdx.x;
  const int wave = tid >> 6;
  const int lane = tid & 63;
  const int ln15 = lane & 15;
  const int lgr = lane >> 4;

  __shared__ unsigned short Ks[2][16 * 512];
  __shared__ unsigned short Vts[2][16 * 512];
  __shared__ unsigned short Ps[4][16 * PS_LD];

  // ---- fused Q load + RMSNorm + RoPE + ATT_SCALE (in registers) ----
  const int srow = q0 + wave * 16 + ln15;    // seq pos within batch (<4096)
  const size_t qrow = (size_t)(b * S_LEN + srow) * QKV_N + h * HD;
  float xq[8][8];
  float ssq = 0.f;
#pragma unroll
  for (int f = 0; f < 8; ++f) {
    const uint4 pv = *(const uint4*)(qkv + qrow + f * 32 + lgr * 8);
    const unsigned int u0 = pv.x, u1 = pv.y, u2 = pv.z, u3 = pv.w;
    xq[f][0] = bf2f((unsigned short)(u0 & 0xffff));
    xq[f][1] = bf2f((unsigned short)(u0 >> 16));
    xq[f][2] = bf2f((unsigned short)(u1 & 0xffff));
    xq[f][3] = bf2f((unsigned short)(u1 >> 16));
    xq[f][4] = bf2f((unsigned short)(u2 & 0xffff));
    xq[f][5] = bf2f((unsigned short)(u2 >> 16));
    xq[f][6] = bf2f((unsigned short)(u3 & 0xffff));
    xq[f][7] = bf2f((unsigned short)(u3 >> 16));
#pragma unroll
    for (int e = 0; e < 8; ++e) ssq += xq[f][e] * xq[f][e];
  }
  // lanes sharing ln15 (lgr = 0..3, lane bits 4-5) hold the 4 row-quarters
  ssq += __shfl_xor(ssq, 16);
  ssq += __shfl_xor(ssq, 32);
  const float qinv = rsqrtf(ssq * (1.0f / 256.0f) + 1e-6f);

  s16x8 qfrag[8];
#pragma unroll
  for (int f = 0; f < 8; ++f) {
    const int c0 = f * 32 + lgr * 8;
    const float4 w0 = *(const float4*)(qw + c0);
    const float4 w1 = *(const float4*)(qw + c0 + 4);
    const float4 cv = *(const float4*)(cosb + (size_t)srow * (HD / 2) + (c0 >> 1));
    const float4 sv = *(const float4*)(sinb + (size_t)srow * (HD / 2) + (c0 >> 1));
    const float wv[8] = {w0.x, w0.y, w0.z, w0.w, w1.x, w1.y, w1.z, w1.w};
    const float cc[4] = {cv.x, cv.y, cv.z, cv.w};
    const float ssn[4] = {sv.x, sv.y, sv.z, sv.w};
    union { unsigned int u4[4]; s16x8 v; } pk;
#pragma unroll
    for (int p = 0; p < 4; ++p) {
      const float a  = xq[f][2 * p]     * qinv * (1.0f + wv[2 * p]);
      const float bb = xq[f][2 * p + 1] * qinv * (1.0f + wv[2 * p + 1]);
      const float o0 = (a * cc[p] - bb * ssn[p]) * ATT_SCALE;
      const float o1 = (a * ssn[p] + bb * cc[p]) * ATT_SCALE;
      pk.u4[p] = (unsigned int)f2bf(o0) | ((unsigned int)f2bf(o1) << 16);
    }
    qfrag[f] = pk.v;
  }

  f32x4 acc[16];
#pragma unroll
  for (int t = 0; t < 16; ++t) acc[t] = (f32x4){0.f, 0.f, 0.f, 0.f};
  float l_part[4] = {0.f, 0.f, 0.f, 0.f};

  const int kt_lo = max(0, q0 - WIN) >> 5;
  const int kt_hi = (q0 + 63) >> 5;
  const unsigned short* kbase = qkv + (size_t)(b * S_LEN) * QKV_N + 4 * HD;
  const unsigned short* vbase = vtb + (size_t)b * (S_LEN / 32) * HD * 32;

  auto stage = [&](int kt, int buf) {
#pragma unroll
    for (int u = 0; u < 4; ++u) {
      const int c = wave * 4 + u;
      const int ct = c >> 3, f = c & 7;
      const unsigned short* gk =
          kbase + (size_t)(kt * 32 + ct * 16 + ln15) * QKV_N + f * 32 + lgr * 8;
      gl2lds16(gk, &Ks[buf][c * 512]);
      const unsigned short* gv =
          vbase + (size_t)kt * (HD * 32) + (size_t)(c * 16 + ln15) * 32 + lgr * 8;
      gl2lds16(gv, &Vts[buf][c * 512]);
    }
  };

  stage(kt_lo, 0);
  __syncthreads();

  unsigned short* psw = Ps[wave];
  const int i_row0 = q0 + wave * 16 + lgr * 4;

  for (int kt = kt_lo; kt <= kt_hi; ++kt) {
    const int cur = (kt - kt_lo) & 1;
    if (kt < kt_hi) stage(kt + 1, cur ^ 1);

    // QK^T
    f32x4 sc[2];
    sc[0] = (f32x4){0.f, 0.f, 0.f, 0.f};
    sc[1] = (f32x4){0.f, 0.f, 0.f, 0.f};
#pragma unroll
    for (int f = 0; f < 8; ++f) {
#pragma unroll
      for (int ct = 0; ct < 2; ++ct) {
        const s16x8 kf = *(const s16x8*)&Ks[cur][(ct * 8 + f) * 512 + lane * 8];
        sc[ct] = __builtin_amdgcn_mfma_f32_16x16x32_bf16(qfrag[f], kf, sc[ct], 0, 0, 0);
      }
    }

    // static-max softmax: p = exp(s - 16), masked to 0
    const int j0 = kt * 32 + ln15;
    float p0[4], p1[4];
#pragma unroll
    for (int r = 0; r < 4; ++r) {
      const int i = i_row0 + r;
      const bool a0 = (j0 <= i) && (i - j0 <= WIN);
      const bool a1 = (j0 + 16 <= i) && (i - (j0 + 16) <= WIN);
      const float e0 = __expf(sc[0][r] - 16.0f);
      const float e1 = __expf(sc[1][r] - 16.0f);
      p0[r] = a0 ? e0 : 0.0f;
      p1[r] = a1 ? e1 : 0.0f;
      l_part[r] += p0[r] + p1[r];
    }
    // packed b32 P writes: col 2*ln15 = key ln15 (ct0), col 2*ln15+1 = key 16+ln15
#pragma unroll
    for (int r = 0; r < 4; ++r) {
      const unsigned int pk = (unsigned int)f2bf(p0[r]) | ((unsigned int)f2bf(p1[r]) << 16);
      *(unsigned int*)&psw[(lgr * 4 + r) * PS_LD + (ln15 << 1)] = pk;
    }
    const s16x8 pf = *(const s16x8*)&psw[ln15 * PS_LD + lgr * 8];
#pragma unroll
    for (int t = 0; t < 16; ++t) {
      const s16x8 vf = *(const s16x8*)&Vts[cur][t * 512 + lane * 8];
      acc[t] = __builtin_amdgcn_mfma_f32_16x16x32_bf16(pf, vf, acc[t], 0, 0, 0);
    }
    __syncthreads();
  }

#pragma unroll
  for (int off = 1; off < 16; off <<= 1)
#pragma unroll
    for (int r = 0; r < 4; ++r) l_part[r] += __shfl_xor(l_part[r], off);

  float inv_l[4];
#pragma unroll
  for (int r = 0; r < 4; ++r) inv_l[r] = 1.0f / l_part[r];
#pragma unroll
  for (int t = 0; t < 16; ++t)
#pragma unroll
    for (int r = 0; r < 4; ++r) {
      const size_t orow = (size_t)(b * S_LEN + q0 + wave * 16 + lgr * 4 + r);
      aob[(orow * NH + h) * HD + t * 16 + ln15] = f2bf(acc[t][r] * inv_l[r]);
    }
}

// ---------------------------------------------------------------------------
extern "C" void kernel_launch(void* const* d_in, const int* in_sizes, int n_in,
                              void* d_out, int out_size, void* d_ws, size_t ws_size,
                              hipStream_t stream) {
  const float* x    = (const float*)d_in[0];
  const float* cosb = (const float*)d_in[1];
  const float* sinb = (const float*)d_in[2];
  const float* Wq   = (const float*)d_in[3];
  const float* Wk   = (const float*)d_in[4];
  const float* Wv   = (const float*)d_in[5];
  const float* Wo   = (const float*)d_in[6];
  const float* qw   = (const float*)d_in[7];
  const float* kw   = (const float*)d_in[8];
  float* out = (float*)d_out;

  unsigned short* ws = (unsigned short*)d_ws;
  unsigned short* xb     = ws;                    // 8192*640  = 5242880
  unsigned short* Wqkvt  = xb + 5242880;          // 1536*640  = 983040
  unsigned short* Wot    = Wqkvt + 983040;        // 640*1024  = 655360
  unsigned short* qkvb   = Wot + 655360;          // 8192*1536 = 12582912
  unsigned short* vtb    = qkvb + 12582912;       // 8192*256  = 2097152
  unsigned short* aob    = vtb + 2097152;         // 8192*1024 = 8388608
  const int M = 2 * S_LEN;

  prep_kernel<<<5520, 256, 0, stream>>>(x, xb, Wq, Wk, Wv, Wo, Wqkvt, Wot);
  gemm_bt<true><<<dim3(QKV_N / 128, M / 128), 256, 0, stream>>>(xb, Wqkvt, qkvb, M, QKV_N, 640);
  normrope_vt_kernel<<<2048 + 256, 256, 0, stream>>>(qkvb, cosb, sinb, kw, vtb);
  attn_mfma_kernel<<<M / 64 * NH, 256, 0, stream>>>(qkvb, vtb, aob, cosb, sinb, qw);
  gemm_bt64<<<dim3(640 / 128, M / 64), 256, 0, stream>>>(aob, Wot, out, M, 640, 1024);
}

// Round 10
// 225.116 us; speedup vs baseline: 1.0009x; 1.0009x over previous
//
#include <hip/hip_runtime.h>
#include <hip/hip_bf16.h>

#define S_LEN 4096
#define NH 4
#define HD 256
#define WIN 512
#define ATT_SCALE 0.0625f   // 256^-0.5
#define QKV_N 1536          // packed q(1024) | k(256) | v(256)

typedef short s16x8 __attribute__((ext_vector_type(8)));
typedef float f32x4 __attribute__((ext_vector_type(4)));

static __device__ inline unsigned short f2bf(float f) {
  union { float f; unsigned int u; } v; v.f = f;
  unsigned int r = v.u + 0x7fff + ((v.u >> 16) & 1);   // RNE
  return (unsigned short)(r >> 16);
}
static __device__ inline float bf2f(unsigned short h) {
  union { unsigned int u; float f; } v; v.u = ((unsigned int)h) << 16;
  return v.f;
}
static __device__ inline void gl2lds16(const void* g, void* l) {
  __builtin_amdgcn_global_load_lds(
      (const __attribute__((address_space(1))) unsigned int*)g,
      (__attribute__((address_space(3))) unsigned int*)l, 16, 0, 0);
}

// ---------------------------------------------------------------------------
// Fused prep: region [0,5120) = x fp32->bf16 cast; then 4 transpose+cast
// weight regions (Wq,Wk,Wv -> packed Wqkvt; Wo -> Wot). One dispatch.
// ---------------------------------------------------------------------------
static __device__ void trcast_tile(const float* __restrict__ src,
                                   unsigned short* __restrict__ dst,
                                   int K, int N, int bn, int bk, int tid,
                                   float* ts /*[64][65]*/) {
#pragma unroll
  for (int it = 0; it < 4; ++it) {
    const int c = it * 256 + tid;
    const int row = c >> 4, col4 = (c & 15) << 2;
    const float4 v = *(const float4*)(src + (size_t)(bk * 64 + row) * N + bn * 64 + col4);
    ts[row * 65 + col4 + 0] = v.x; ts[row * 65 + col4 + 1] = v.y;
    ts[row * 65 + col4 + 2] = v.z; ts[row * 65 + col4 + 3] = v.w;
  }
  __syncthreads();
#pragma unroll
  for (int it = 0; it < 4; ++it) {
    const int c = it * 256 + tid;
    const int nrow = c >> 4, kc4 = (c & 15) << 2;
    const unsigned int p0 = f2bf(ts[(kc4 + 0) * 65 + nrow]) | ((unsigned int)f2bf(ts[(kc4 + 1) * 65 + nrow]) << 16);
    const unsigned int p1 = f2bf(ts[(kc4 + 2) * 65 + nrow]) | ((unsigned int)f2bf(ts[(kc4 + 3) * 65 + nrow]) << 16);
    *(uint2*)(dst + (size_t)(bn * 64 + nrow) * K + bk * 64 + kc4) = make_uint2(p0, p1);
  }
}

__global__ __launch_bounds__(256) void prep_kernel(
    const float* __restrict__ x, unsigned short* __restrict__ xb,
    const float* __restrict__ Wq, const float* __restrict__ Wk,
    const float* __restrict__ Wv, const float* __restrict__ Wo,
    unsigned short* __restrict__ Wqkvt, unsigned short* __restrict__ Wot) {
  __shared__ float ts[64 * 65];
  const int g = blockIdx.x;
  const int tid = threadIdx.x;
  if (g < 5120) {                    // cvt x -> bf16 (1310720 float4 elems)
    const int t = g * 256 + tid;
    const float4 v = ((const float4*)x)[t];
    const unsigned int p0 = f2bf(v.x) | ((unsigned int)f2bf(v.y) << 16);
    const unsigned int p1 = f2bf(v.z) | ((unsigned int)f2bf(v.w) << 16);
    *(uint2*)(xb + (size_t)t * 4) = make_uint2(p0, p1);
  } else if (g < 5280) {             // Wq: N=1024 (16), K=640 (10)
    const int g2 = g - 5120;
    trcast_tile(Wq, Wqkvt, 640, 1024, g2 & 15, g2 >> 4, tid, ts);
  } else if (g < 5320) {             // Wk: N=256 (4), K=640 (10)
    const int g2 = g - 5280;
    trcast_tile(Wk, Wqkvt + (size_t)1024 * 640, 640, 256, g2 & 3, g2 >> 2, tid, ts);
  } else if (g < 5360) {             // Wv
    const int g2 = g - 5320;
    trcast_tile(Wv, Wqkvt + (size_t)1280 * 640, 640, 256, g2 & 3, g2 >> 2, tid, ts);
  } else {                           // Wo: N=640 (10), K=1024 (16)
    const int g2 = g - 5360;
    trcast_tile(Wo, Wot, 1024, 640, g2 % 10, g2 / 10, tid, ts);
  }
}

// ---------------------------------------------------------------------------
// bf16 MFMA GEMM (m97 structure): C[M,N] = A[M,K] @ Bt[N,K]^T. 128x128 tile.
// ---------------------------------------------------------------------------
template <bool BF16OUT>
__global__ __launch_bounds__(256) void gemm_bt(const unsigned short* __restrict__ A,
                                               const unsigned short* __restrict__ Bt,
                                               void* __restrict__ Cv,
                                               int M, int N, int K) {
  __shared__ unsigned short As[128 * 32];
  __shared__ unsigned short Bs[128 * 32];
  const int tid = threadIdx.x;
  const int wave = tid >> 6, lane = tid & 63;
  const int ln15 = lane & 15, lgr = lane >> 4;
  const int bm = blockIdx.y, bn = blockIdx.x;
  const int wr = wave & 1, wc = wave >> 1;
  const unsigned short* Ab = A + (size_t)bm * 128 * K;
  const unsigned short* Bb = Bt + (size_t)bn * 128 * K;

  f32x4 acc[4][4];
#pragma unroll
  for (int mt = 0; mt < 4; ++mt)
#pragma unroll
    for (int nt = 0; nt < 4; ++nt) acc[mt][nt] = (f32x4){0.f, 0.f, 0.f, 0.f};

  for (int kt = 0; kt < K; kt += 32) {
#pragma unroll
    for (int i = 0; i < 2; ++i) {
      const int c = tid + 256 * i;
      const int row = c >> 2, kc = (c & 3) << 3;
      gl2lds16(Ab + (size_t)row * K + kt + kc, &As[c * 8]);
      gl2lds16(Bb + (size_t)row * K + kt + kc, &Bs[c * 8]);
    }
    __syncthreads();
    s16x8 af[4], bfr[4];
#pragma unroll
    for (int t = 0; t < 4; ++t) {
      af[t]  = *(const s16x8*)&As[(wr * 64 + t * 16 + ln15) * 32 + lgr * 8];
      bfr[t] = *(const s16x8*)&Bs[(wc * 64 + t * 16 + ln15) * 32 + lgr * 8];
    }
#pragma unroll
    for (int mt = 0; mt < 4; ++mt)
#pragma unroll
      for (int nt = 0; nt < 4; ++nt)
        acc[mt][nt] = __builtin_amdgcn_mfma_f32_16x16x32_bf16(af[mt], bfr[nt], acc[mt][nt], 0, 0, 0);
    __syncthreads();
  }

#pragma unroll
  for (int mt = 0; mt < 4; ++mt)
#pragma unroll
    for (int nt = 0; nt < 4; ++nt)
#pragma unroll
      for (int r = 0; r < 4; ++r) {
        const size_t row = bm * 128 + wr * 64 + mt * 16 + lgr * 4 + r;
        const size_t col = bn * 128 + wc * 64 + nt * 16 + ln15;
        if (BF16OUT) ((unsigned short*)Cv)[row * N + col] = f2bf(acc[mt][nt][r]);
        else         ((float*)Cv)[row * N + col] = acc[mt][nt][r];
      }
}

// ---------------------------------------------------------------------------
// 64x128-tile variant (fp32 out) for the output projection: N=640 -> 5 n-tiles,
// grid 128x5 = 640 blocks (2.5/CU vs 1.25/CU at 128x128 -> smaller tail).
// Wave wc owns 32 n-cols; acc 4x2 per wave.
// ---------------------------------------------------------------------------
__global__ __launch_bounds__(256) void gemm_bt64(const unsigned short* __restrict__ A,
                                                 const unsigned short* __restrict__ Bt,
                                                 float* __restrict__ C,
                                                 int M, int N, int K) {
  __shared__ unsigned short As[64 * 32];
  __shared__ unsigned short Bs[128 * 32];
  const int tid = threadIdx.x;
  const int wave = tid >> 6, lane = tid & 63;
  const int ln15 = lane & 15, lgr = lane >> 4;
  const int bm = blockIdx.y, bn = blockIdx.x;
  const unsigned short* Ab = A + (size_t)bm * 64 * K;
  const unsigned short* Bb = Bt + (size_t)bn * 128 * K;

  f32x4 acc[4][2];
#pragma unroll
  for (int mt = 0; mt < 4; ++mt)
#pragma unroll
    for (int nt = 0; nt < 2; ++nt) acc[mt][nt] = (f32x4){0.f, 0.f, 0.f, 0.f};

  for (int kt = 0; kt < K; kt += 32) {
    {
      const int row = tid >> 2, kc = (tid & 3) << 3;
      gl2lds16(Ab + (size_t)row * K + kt + kc, &As[tid * 8]);
#pragma unroll
      for (int i = 0; i < 2; ++i) {
        const int c = tid + 256 * i;
        const int brow = c >> 2, bkc = (c & 3) << 3;
        gl2lds16(Bb + (size_t)brow * K + kt + bkc, &Bs[c * 8]);
      }
    }
    __syncthreads();
    s16x8 af[4], bfr[2];
#pragma unroll
    for (int t = 0; t < 4; ++t)
      af[t] = *(const s16x8*)&As[(t * 16 + ln15) * 32 + lgr * 8];
#pragma unroll
    for (int t = 0; t < 2; ++t)
      bfr[t] = *(const s16x8*)&Bs[(wave * 32 + t * 16 + ln15) * 32 + lgr * 8];
#pragma unroll
    for (int mt = 0; mt < 4; ++mt)
#pragma unroll
      for (int nt = 0; nt < 2; ++nt)
        acc[mt][nt] = __builtin_amdgcn_mfma_f32_16x16x32_bf16(af[mt], bfr[nt], acc[mt][nt], 0, 0, 0);
    __syncthreads();
  }

#pragma unroll
  for (int mt = 0; mt < 4; ++mt)
#pragma unroll
    for (int nt = 0; nt < 2; ++nt)
#pragma unroll
      for (int r = 0; r < 4; ++r) {
        const size_t row = bm * 64 + mt * 16 + lgr * 4 + r;
        const size_t col = bn * 128 + wave * 32 + nt * 16 + ln15;
        C[row * N + col] = acc[mt][nt][r];
      }
}

// ---------------------------------------------------------------------------
// K-only RMSNorm+RoPE (blocks [0,2048)) + V-transpose (blocks [2048,2304)).
//
// Q rows are fused into attn's Q-fragment load (each Q row has exactly one
// consumer under MQA). K rows stay precomputed (each re-read ~36x).
//
// Norm part wave-per-row: one wave = one 256-elem row, 4 elems/lane via uint2,
// wave-local shfl reduce, zero barriers/LDS.
//
// V-transpose (unchanged) uses INTERLEAVED key storage order
// s = 2*(jj&15) | (jj>>4), so attention's P round-trip can write packed b32
// pairs (PV is key-permutation invariant as long as P cols and Vt cols share
// the order).
// ---------------------------------------------------------------------------
__global__ __launch_bounds__(256) void normrope_vt_kernel(
    unsigned short* __restrict__ qkv,
    const float* __restrict__ cosb, const float* __restrict__ sinb,
    const float* __restrict__ kw,
    unsigned short* __restrict__ vtb) {
  const int bid = blockIdx.x;
  const int tid = threadIdx.x;
  if (bid < 2048) {
    const int lane = tid & 63, wave = tid >> 6;
    const int bs = bid * 4 + wave;           // 0..8191 (K row id)
    const int s = bs & (S_LEN - 1);
    unsigned short* row = qkv + (size_t)bs * QKV_N + 4 * HD;
    // lane handles elements [4*lane, 4*lane+4) = rope pairs pi=2*lane, 2*lane+1
    const uint2 pv = *(const uint2*)(row + 4 * lane);
    float xv[4];
    xv[0] = bf2f((unsigned short)(pv.x & 0xffff));
    xv[1] = bf2f((unsigned short)(pv.x >> 16));
    xv[2] = bf2f((unsigned short)(pv.y & 0xffff));
    xv[3] = bf2f((unsigned short)(pv.y >> 16));
    float ssq = xv[0] * xv[0] + xv[1] * xv[1] + xv[2] * xv[2] + xv[3] * xv[3];
#pragma unroll
    for (int off = 32; off > 0; off >>= 1) ssq += __shfl_xor(ssq, off);
    const float inv = rsqrtf(ssq * (1.0f / 256.0f) + 1e-6f);
    const float4 wv = *(const float4*)(kw + 4 * lane);
    const float2 cv = *(const float2*)(cosb + (size_t)s * (HD / 2) + 2 * lane);
    const float2 sv = *(const float2*)(sinb + (size_t)s * (HD / 2) + 2 * lane);
    const float a0 = xv[0] * inv * (1.0f + wv.x);
    const float b0 = xv[1] * inv * (1.0f + wv.y);
    const float a1 = xv[2] * inv * (1.0f + wv.z);
    const float b1 = xv[3] * inv * (1.0f + wv.w);
    const float o0 = a0 * cv.x - b0 * sv.x;
    const float o1 = a0 * sv.x + b0 * cv.x;
    const float o2 = a1 * cv.y - b1 * sv.y;
    const float o3 = a1 * sv.y + b1 * cv.y;
    uint2 ov;
    ov.x = (unsigned int)f2bf(o0) | ((unsigned int)f2bf(o1) << 16);
    ov.y = (unsigned int)f2bf(o2) | ((unsigned int)f2bf(o3) << 16);
    *(uint2*)(row + 4 * lane) = ov;
  } else {
    __shared__ unsigned short ts[32][264];
    const int g2 = bid - 2048;
    const int b = g2 >> 7, jt = g2 & 127;
    const unsigned short* src = qkv + ((size_t)(b * S_LEN) + jt * 32) * QKV_N + 5 * HD;
#pragma unroll
    for (int it = 0; it < 4; ++it) {
      const int c = tid + 256 * it;
      const int row = c >> 5, col8 = (c & 31) << 3;
      *(uint4*)&ts[row][col8] = *(const uint4*)(src + (size_t)row * QKV_N + col8);
    }
    __syncthreads();
    unsigned short tmp[32];
#pragma unroll
    for (int s2 = 0; s2 < 32; ++s2) {
      const int jj = (s2 >> 1) | ((s2 & 1) << 4);   // inverse of s = 2*(jj&15)|(jj>>4)
      tmp[s2] = ts[jj][tid];
    }
    unsigned short* dst = vtb + ((size_t)(b * 128 + jt) * 256 + tid) * 32;
#pragma unroll
    for (int wq = 0; wq < 4; ++wq) *(uint4*)(dst + wq * 8) = *(uint4*)(tmp + wq * 8);
  }
}

// ---------------------------------------------------------------------------
// Flash-style sliding-window MQA, bf16 MFMA — R0 loop structure + fused Q
// RMSNorm+RoPE, LOW-REGISTER version.
//
// R8 post-mortem: float xq[8][8] (64 fp32 regs live across the reduce +
// transform) pushed VGPR 88->148, past the ~128 occupancy boundary ->
// 1 block/CU -> 80us. Fix: store the raw Q row PACKED bf16 in qfrag itself
// (32 VGPRs, same registers the fragments occupy anyway); unpack transiently
// for ssq (pass A), then unpack/transform/repack in place per f (pass B).
// Identical math, peak live ~100-115 VGPR -> 2 blocks/CU restored.
// ---------------------------------------------------------------------------
#define PS_LD 40

__global__ __launch_bounds__(256) void attn_mfma_kernel(
    const unsigned short* __restrict__ qkv, const unsigned short* __restrict__ vtb,
    unsigned short* __restrict__ aob,
    const float* __restrict__ cosb, const float* __restrict__ sinb,
    const float* __restrict__ qw) {
  const int g = blockIdx.x;
  const int xcd = g & 7, slot = g >> 3;      // assume block j -> XCD j%8
  const int h = slot >> 4;                   // 0..3
  const int qt = xcd * 16 + (slot & 15);     // 0..127
  const int b = qt >> 6;
  const int q0 = (qt & 63) << 6;
  const int tid = threadIdx.x;
  const int wave = tid >> 6;
  const int lane = tid & 63;
  const int ln15 = lane & 15;
  const int lgr = lane >> 4;

  __shared__ unsigned short Ks[2][16 * 512];
  __shared__ unsigned short Vts[2][16 * 512];
  __shared__ unsigned short Ps[4][16 * PS_LD];

  // ---- fused Q load + RMSNorm + RoPE + ATT_SCALE, packed-bf16 two-pass ----
  const int srow = q0 + wave * 16 + ln15;    // seq pos within batch (<4096)
  const size_t qrow = (size_t)(b * S_LEN + srow) * QKV_N + h * HD;
  s16x8 qfrag[8];
  float ssq = 0.f;
#pragma unroll
  for (int f = 0; f < 8; ++f) {              // pass A: raw load + ssq
    qfrag[f] = *(const s16x8*)(qkv + qrow + f * 32 + lgr * 8);
#pragma unroll
    for (int e = 0; e < 8; ++e) {
      const float xx = bf2f((unsigned short)qfrag[f][e]);
      ssq += xx * xx;
    }
  }
  // lanes sharing ln15 (lgr = 0..3, lane bits 4-5) hold the 4 row-quarters
  ssq += __shfl_xor(ssq, 16);
  ssq += __shfl_xor(ssq, 32);
  const float qinv = rsqrtf(ssq * (1.0f / 256.0f) + 1e-6f);

#pragma unroll
  for (int f = 0; f < 8; ++f) {              // pass B: transform in place
    const int c0 = f * 32 + lgr * 8;
    const float4 w0 = *(const float4*)(qw + c0);
    const float4 w1 = *(const float4*)(qw + c0 + 4);
    const float4 cv = *(const float4*)(cosb + (size_t)srow * (HD / 2) + (c0 >> 1));
    const float4 sv = *(const float4*)(sinb + (size_t)srow * (HD / 2) + (c0 >> 1));
    const float wv[8] = {w0.x, w0.y, w0.z, w0.w, w1.x, w1.y, w1.z, w1.w};
    const float cc[4] = {cv.x, cv.y, cv.z, cv.w};
    const float ssn[4] = {sv.x, sv.y, sv.z, sv.w};
    union { unsigned int u4[4]; s16x8 v; } pk;
#pragma unroll
    for (int p = 0; p < 4; ++p) {
      const float a  = bf2f((unsigned short)qfrag[f][2 * p])     * qinv * (1.0f + wv[2 * p]);
      const float bb = bf2f((unsigned short)qfrag[f][2 * p + 1]) * qinv * (1.0f + wv[2 * p + 1]);
      const float o0 = (a * cc[p] - bb * ssn[p]) * ATT_SCALE;
      const float o1 = (a * ssn[p] + bb * cc[p]) * ATT_SCALE;
      pk.u4[p] = (unsigned int)f2bf(o0) | ((unsigned int)f2bf(o1) << 16);
    }
    qfrag[f] = pk.v;
  }

  f32x4 acc[16];
#pragma unroll
  for (int t = 0; t < 16; ++t) acc[t] = (f32x4){0.f, 0.f, 0.f, 0.f};
  float l_part[4] = {0.f, 0.f, 0.f, 0.f};

  const int kt_lo = max(0, q0 - WIN) >> 5;
  const int kt_hi = (q0 + 63) >> 5;
  const unsigned short* kbase = qkv + (size_t)(b * S_LEN) * QKV_N + 4 * HD;
  const unsigned short* vbase = vtb + (size_t)b * (S_LEN / 32) * HD * 32;

  auto stage = [&](int kt, int buf) {
#pragma unroll
    for (int u = 0; u < 4; ++u) {
      const int c = wave * 4 + u;
      const int ct = c >> 3, f = c & 7;
      const unsigned short* gk =
          kbase + (size_t)(kt * 32 + ct * 16 + ln15) * QKV_N + f * 32 + lgr * 8;
      gl2lds16(gk, &Ks[buf][c * 512]);
      const unsigned short* gv =
          vbase + (size_t)kt * (HD * 32) + (size_t)(c * 16 + ln15) * 32 + lgr * 8;
      gl2lds16(gv, &Vts[buf][c * 512]);
    }
  };

  stage(kt_lo, 0);
  __syncthreads();

  unsigned short* psw = Ps[wave];
  const int i_row0 = q0 + wave * 16 + lgr * 4;

  for (int kt = kt_lo; kt <= kt_hi; ++kt) {
    const int cur = (kt - kt_lo) & 1;
    if (kt < kt_hi) stage(kt + 1, cur ^ 1);

    // QK^T
    f32x4 sc[2];
    sc[0] = (f32x4){0.f, 0.f, 0.f, 0.f};
    sc[1] = (f32x4){0.f, 0.f, 0.f, 0.f};
#pragma unroll
    for (int f = 0; f < 8; ++f) {
#pragma unroll
      for (int ct = 0; ct < 2; ++ct) {
        const s16x8 kf = *(const s16x8*)&Ks[cur][(ct * 8 + f) * 512 + lane * 8];
        sc[ct] = __builtin_amdgcn_mfma_f32_16x16x32_bf16(qfrag[f], kf, sc[ct], 0, 0, 0);
      }
    }

    // static-max softmax: p = exp(s - 16), masked to 0
    const int j0 = kt * 32 + ln15;
    float p0[4], p1[4];
#pragma unroll
    for (int r = 0; r < 4; ++r) {
      const int i = i_row0 + r;
      const bool a0 = (j0 <= i) && (i - j0 <= WIN);
      const bool a1 = (j0 + 16 <= i) && (i - (j0 + 16) <= WIN);
      const float e0 = __expf(sc[0][r] - 16.0f);
      const float e1 = __expf(sc[1][r] - 16.0f);
      p0[r] = a0 ? e0 : 0.0f;
      p1[r] = a1 ? e1 : 0.0f;
      l_part[r] += p0[r] + p1[r];
    }
    // packed b32 P writes: col 2*ln15 = key ln15 (ct0), col 2*ln15+1 = key 16+ln15
#pragma unroll
    for (int r = 0; r < 4; ++r) {
      const unsigned int pk = (unsigned int)f2bf(p0[r]) | ((unsigned int)f2bf(p1[r]) << 16);
      *(unsigned int*)&psw[(lgr * 4 + r) * PS_LD + (ln15 << 1)] = pk;
    }
    const s16x8 pf = *(const s16x8*)&psw[ln15 * PS_LD + lgr * 8];
#pragma unroll
    for (int t = 0; t < 16; ++t) {
      const s16x8 vf = *(const s16x8*)&Vts[cur][t * 512 + lane * 8];
      acc[t] = __builtin_amdgcn_mfma_f32_16x16x32_bf16(pf, vf, acc[t], 0, 0, 0);
    }
    __syncthreads();
  }

#pragma unroll
  for (int off = 1; off < 16; off <<= 1)
#pragma unroll
    for (int r = 0; r < 4; ++r) l_part[r] += __shfl_xor(l_part[r], off);

  float inv_l[4];
#pragma unroll
  for (int r = 0; r < 4; ++r) inv_l[r] = 1.0f / l_part[r];
#pragma unroll
  for (int t = 0; t < 16; ++t)
#pragma unroll
    for (int r = 0; r < 4; ++r) {
      const size_t orow = (size_t)(b * S_LEN + q0 + wave * 16 + lgr * 4 + r);
      aob[(orow * NH + h) * HD + t * 16 + ln15] = f2bf(acc[t][r] * inv_l[r]);
    }
}

// ---------------------------------------------------------------------------
extern "C" void kernel_launch(void* const* d_in, const int* in_sizes, int n_in,
                              void* d_out, int out_size, void* d_ws, size_t ws_size,
                              hipStream_t stream) {
  const float* x    = (const float*)d_in[0];
  const float* cosb = (const float*)d_in[1];
  const float* sinb = (const float*)d_in[2];
  const float* Wq   = (const float*)d_in[3];
  const float* Wk   = (const float*)d_in[4];
  const float* Wv   = (const float*)d_in[5];
  const float* Wo   = (const float*)d_in[6];
  const float* qw   = (const float*)d_in[7];
  const float* kw   = (const float*)d_in[8];
  float* out = (float*)d_out;

  unsigned short* ws = (unsigned short*)d_ws;
  unsigned short* xb     = ws;                    // 8192*640  = 5242880
  unsigned short* Wqkvt  = xb + 5242880;          // 1536*640  = 983040
  unsigned short* Wot    = Wqkvt + 983040;        // 640*1024  = 655360
  unsigned short* qkvb   = Wot + 655360;          // 8192*1536 = 12582912
  unsigned short* vtb    = qkvb + 12582912;       // 8192*256  = 2097152
  unsigned short* aob    = vtb + 2097152;         // 8192*1024 = 8388608
  const int M = 2 * S_LEN;

  prep_kernel<<<5520, 256, 0, stream>>>(x, xb, Wq, Wk, Wv, Wo, Wqkvt, Wot);
  gemm_bt<true><<<dim3(QKV_N / 128, M / 128), 256, 0, stream>>>(xb, Wqkvt, qkvb, M, QKV_N, 640);
  normrope_vt_kernel<<<2048 + 256, 256, 0, stream>>>(qkvb, cosb, sinb, kw, vtb);
  attn_mfma_kernel<<<M / 64 * NH, 256, 0, stream>>>(qkvb, vtb, aob, cosb, sinb, qw);
  gemm_bt64<<<dim3(640 / 128, M / 64), 256, 0, stream>>>(aob, Wot, out, M, 640, 1024);
}

// Round 11
// 197.934 us; speedup vs baseline: 1.1384x; 1.1373x over previous
//
#include <hip/hip_runtime.h>
#include <hip/hip_bf16.h>

#define S_LEN 4096
#define NH 4
#define HD 256
#define WIN 512
#define ATT_SCALE 0.0625f   // 256^-0.5
#define QKV_N 1536          // packed q(1024) | k(256) | v(256)

typedef short s16x8 __attribute__((ext_vector_type(8)));
typedef float f32x4 __attribute__((ext_vector_type(4)));

static __device__ inline unsigned short f2bf(float f) {
  union { float f; unsigned int u; } v; v.f = f;
  unsigned int r = v.u + 0x7fff + ((v.u >> 16) & 1);   // RNE
  return (unsigned short)(r >> 16);
}
static __device__ inline float bf2f(unsigned short h) {
  union { unsigned int u; float f; } v; v.u = ((unsigned int)h) << 16;
  return v.f;
}
static __device__ inline void gl2lds16(const void* g, void* l) {
  __builtin_amdgcn_global_load_lds(
      (const __attribute__((address_space(1))) unsigned int*)g,
      (__attribute__((address_space(3))) unsigned int*)l, 16, 0, 0);
}

// ---------------------------------------------------------------------------
// Fused prep: region [0,5120) = x fp32->bf16 cast; then 4 transpose+cast
// weight regions (Wq,Wk,Wv -> packed Wqkvt; Wo -> Wot). One dispatch.
// ---------------------------------------------------------------------------
static __device__ void trcast_tile(const float* __restrict__ src,
                                   unsigned short* __restrict__ dst,
                                   int K, int N, int bn, int bk, int tid,
                                   float* ts /*[64][65]*/) {
#pragma unroll
  for (int it = 0; it < 4; ++it) {
    const int c = it * 256 + tid;
    const int row = c >> 4, col4 = (c & 15) << 2;
    const float4 v = *(const float4*)(src + (size_t)(bk * 64 + row) * N + bn * 64 + col4);
    ts[row * 65 + col4 + 0] = v.x; ts[row * 65 + col4 + 1] = v.y;
    ts[row * 65 + col4 + 2] = v.z; ts[row * 65 + col4 + 3] = v.w;
  }
  __syncthreads();
#pragma unroll
  for (int it = 0; it < 4; ++it) {
    const int c = it * 256 + tid;
    const int nrow = c >> 4, kc4 = (c & 15) << 2;
    const unsigned int p0 = f2bf(ts[(kc4 + 0) * 65 + nrow]) | ((unsigned int)f2bf(ts[(kc4 + 1) * 65 + nrow]) << 16);
    const unsigned int p1 = f2bf(ts[(kc4 + 2) * 65 + nrow]) | ((unsigned int)f2bf(ts[(kc4 + 3) * 65 + nrow]) << 16);
    *(uint2*)(dst + (size_t)(bn * 64 + nrow) * K + bk * 64 + kc4) = make_uint2(p0, p1);
  }
}

__global__ __launch_bounds__(256) void prep_kernel(
    const float* __restrict__ x, unsigned short* __restrict__ xb,
    const float* __restrict__ Wq, const float* __restrict__ Wk,
    const float* __restrict__ Wv, const float* __restrict__ Wo,
    unsigned short* __restrict__ Wqkvt, unsigned short* __restrict__ Wot) {
  __shared__ float ts[64 * 65];
  const int g = blockIdx.x;
  const int tid = threadIdx.x;
  if (g < 5120) {                    // cvt x -> bf16 (1310720 float4 elems)
    const int t = g * 256 + tid;
    const float4 v = ((const float4*)x)[t];
    const unsigned int p0 = f2bf(v.x) | ((unsigned int)f2bf(v.y) << 16);
    const unsigned int p1 = f2bf(v.z) | ((unsigned int)f2bf(v.w) << 16);
    *(uint2*)(xb + (size_t)t * 4) = make_uint2(p0, p1);
  } else if (g < 5280) {             // Wq: N=1024 (16), K=640 (10)
    const int g2 = g - 5120;
    trcast_tile(Wq, Wqkvt, 640, 1024, g2 & 15, g2 >> 4, tid, ts);
  } else if (g < 5320) {             // Wk: N=256 (4), K=640 (10)
    const int g2 = g - 5280;
    trcast_tile(Wk, Wqkvt + (size_t)1024 * 640, 640, 256, g2 & 3, g2 >> 2, tid, ts);
  } else if (g < 5360) {             // Wv
    const int g2 = g - 5320;
    trcast_tile(Wv, Wqkvt + (size_t)1280 * 640, 640, 256, g2 & 3, g2 >> 2, tid, ts);
  } else {                           // Wo: N=640 (10), K=1024 (16)
    const int g2 = g - 5360;
    trcast_tile(Wo, Wot, 1024, 640, g2 % 10, g2 / 10, tid, ts);
  }
}

// ---------------------------------------------------------------------------
// bf16 MFMA GEMM (m97 structure): C[M,N] = A[M,K] @ Bt[N,K]^T. 128x128 tile.
// ---------------------------------------------------------------------------
template <bool BF16OUT>
__global__ __launch_bounds__(256) void gemm_bt(const unsigned short* __restrict__ A,
                                               const unsigned short* __restrict__ Bt,
                                               void* __restrict__ Cv,
                                               int M, int N, int K) {
  __shared__ unsigned short As[128 * 32];
  __shared__ unsigned short Bs[128 * 32];
  const int tid = threadIdx.x;
  const int wave = tid >> 6, lane = tid & 63;
  const int ln15 = lane & 15, lgr = lane >> 4;
  const int bm = blockIdx.y, bn = blockIdx.x;
  const int wr = wave & 1, wc = wave >> 1;
  const unsigned short* Ab = A + (size_t)bm * 128 * K;
  const unsigned short* Bb = Bt + (size_t)bn * 128 * K;

  f32x4 acc[4][4];
#pragma unroll
  for (int mt = 0; mt < 4; ++mt)
#pragma unroll
    for (int nt = 0; nt < 4; ++nt) acc[mt][nt] = (f32x4){0.f, 0.f, 0.f, 0.f};

  for (int kt = 0; kt < K; kt += 32) {
#pragma unroll
    for (int i = 0; i < 2; ++i) {
      const int c = tid + 256 * i;
      const int row = c >> 2, kc = (c & 3) << 3;
      gl2lds16(Ab + (size_t)row * K + kt + kc, &As[c * 8]);
      gl2lds16(Bb + (size_t)row * K + kt + kc, &Bs[c * 8]);
    }
    __syncthreads();
    s16x8 af[4], bfr[4];
#pragma unroll
    for (int t = 0; t < 4; ++t) {
      af[t]  = *(const s16x8*)&As[(wr * 64 + t * 16 + ln15) * 32 + lgr * 8];
      bfr[t] = *(const s16x8*)&Bs[(wc * 64 + t * 16 + ln15) * 32 + lgr * 8];
    }
#pragma unroll
    for (int mt = 0; mt < 4; ++mt)
#pragma unroll
      for (int nt = 0; nt < 4; ++nt)
        acc[mt][nt] = __builtin_amdgcn_mfma_f32_16x16x32_bf16(af[mt], bfr[nt], acc[mt][nt], 0, 0, 0);
    __syncthreads();
  }

#pragma unroll
  for (int mt = 0; mt < 4; ++mt)
#pragma unroll
    for (int nt = 0; nt < 4; ++nt)
#pragma unroll
      for (int r = 0; r < 4; ++r) {
        const size_t row = bm * 128 + wr * 64 + mt * 16 + lgr * 4 + r;
        const size_t col = bn * 128 + wc * 64 + nt * 16 + ln15;
        if (BF16OUT) ((unsigned short*)Cv)[row * N + col] = f2bf(acc[mt][nt][r]);
        else         ((float*)Cv)[row * N + col] = acc[mt][nt][r];
      }
}

// ---------------------------------------------------------------------------
// 64x128-tile variant (fp32 out) for the output projection: N=640 -> 5 n-tiles,
// grid 128x5 = 640 blocks (2.5/CU vs 1.25/CU at 128x128 -> smaller tail).
// Wave wc owns 32 n-cols; acc 4x2 per wave.
// ---------------------------------------------------------------------------
__global__ __launch_bounds__(256) void gemm_bt64(const unsigned short* __restrict__ A,
                                                 const unsigned short* __restrict__ Bt,
                                                 float* __restrict__ C,
                                                 int M, int N, int K) {
  __shared__ unsigned short As[64 * 32];
  __shared__ unsigned short Bs[128 * 32];
  const int tid = threadIdx.x;
  const int wave = tid >> 6, lane = tid & 63;
  const int ln15 = lane & 15, lgr = lane >> 4;
  const int bm = blockIdx.y, bn = blockIdx.x;
  const unsigned short* Ab = A + (size_t)bm * 64 * K;
  const unsigned short* Bb = Bt + (size_t)bn * 128 * K;

  f32x4 acc[4][2];
#pragma unroll
  for (int mt = 0; mt < 4; ++mt)
#pragma unroll
    for (int nt = 0; nt < 2; ++nt) acc[mt][nt] = (f32x4){0.f, 0.f, 0.f, 0.f};

  for (int kt = 0; kt < K; kt += 32) {
    {
      const int row = tid >> 2, kc = (tid & 3) << 3;
      gl2lds16(Ab + (size_t)row * K + kt + kc, &As[tid * 8]);
#pragma unroll
      for (int i = 0; i < 2; ++i) {
        const int c = tid + 256 * i;
        const int brow = c >> 2, bkc = (c & 3) << 3;
        gl2lds16(Bb + (size_t)brow * K + kt + bkc, &Bs[c * 8]);
      }
    }
    __syncthreads();
    s16x8 af[4], bfr[2];
#pragma unroll
    for (int t = 0; t < 4; ++t)
      af[t] = *(const s16x8*)&As[(t * 16 + ln15) * 32 + lgr * 8];
#pragma unroll
    for (int t = 0; t < 2; ++t)
      bfr[t] = *(const s16x8*)&Bs[(wave * 32 + t * 16 + ln15) * 32 + lgr * 8];
#pragma unroll
    for (int mt = 0; mt < 4; ++mt)
#pragma unroll
      for (int nt = 0; nt < 2; ++nt)
        acc[mt][nt] = __builtin_amdgcn_mfma_f32_16x16x32_bf16(af[mt], bfr[nt], acc[mt][nt], 0, 0, 0);
    __syncthreads();
  }

#pragma unroll
  for (int mt = 0; mt < 4; ++mt)
#pragma unroll
    for (int nt = 0; nt < 2; ++nt)
#pragma unroll
      for (int r = 0; r < 4; ++r) {
        const size_t row = bm * 64 + mt * 16 + lgr * 4 + r;
        const size_t col = bn * 128 + wave * 32 + nt * 16 + ln15;
        C[row * N + col] = acc[mt][nt][r];
      }
}

// ---------------------------------------------------------------------------
// Fused RMSNorm+RoPE (blocks [0,10240)) + V-transpose (blocks [10240,10496)).
// (R6 verified config: Q-fusion into attn abandoned after two VGPR-cliff
// regressions, R8/R10: compiler hoists pass-B coefficient loads -> 148 VGPR
// -> 1 block/CU -> 80us attn. This separate-pass version keeps attn at 88.)
//
// Norm part wave-per-row: one wave = one 256-elem row, 4 elems/lane via uint2,
// wave-local shfl reduce only -- zero barriers, zero LDS, 4 rows per block.
//
// V-transpose uses INTERLEAVED key storage order s = 2*(jj&15) | (jj>>4), so
// attention's P round-trip can write packed b32 pairs (PV is key-permutation
// invariant as long as P cols and Vt cols share the order).
// ---------------------------------------------------------------------------
__global__ __launch_bounds__(256) void normrope_vt_kernel(
    unsigned short* __restrict__ qkv,
    const float* __restrict__ cosb, const float* __restrict__ sinb,
    const float* __restrict__ qw, const float* __restrict__ kw,
    unsigned short* __restrict__ vtb) {
  const int bid = blockIdx.x;
  const int tid = threadIdx.x;
  if (bid < 10240) {
    const int lane = tid & 63, wave = tid >> 6;
    const int idx = bid * 4 + wave;          // 0..40959 (row id)
    const int h = idx % 5;
    const int bs = idx / 5;
    const int s = bs & (S_LEN - 1);
    unsigned short* base = qkv + (size_t)bs * QKV_N;
    unsigned short* row; const float* w; float oscale;
    if (h < 4) { row = base + h * HD;  w = qw; oscale = ATT_SCALE; }
    else       { row = base + 4 * HD;  w = kw; oscale = 1.0f; }
    // lane handles elements [4*lane, 4*lane+4) = rope pairs pi=2*lane, 2*lane+1
    const uint2 pv = *(const uint2*)(row + 4 * lane);
    float xv[4];
    xv[0] = bf2f((unsigned short)(pv.x & 0xffff));
    xv[1] = bf2f((unsigned short)(pv.x >> 16));
    xv[2] = bf2f((unsigned short)(pv.y & 0xffff));
    xv[3] = bf2f((unsigned short)(pv.y >> 16));
    float ssq = xv[0] * xv[0] + xv[1] * xv[1] + xv[2] * xv[2] + xv[3] * xv[3];
#pragma unroll
    for (int off = 32; off > 0; off >>= 1) ssq += __shfl_xor(ssq, off);
    const float inv = rsqrtf(ssq * (1.0f / 256.0f) + 1e-6f);
    const float4 wv = *(const float4*)(w + 4 * lane);
    const float2 cv = *(const float2*)(cosb + (size_t)s * (HD / 2) + 2 * lane);
    const float2 sv = *(const float2*)(sinb + (size_t)s * (HD / 2) + 2 * lane);
    const float a0 = xv[0] * inv * (1.0f + wv.x);
    const float b0 = xv[1] * inv * (1.0f + wv.y);
    const float a1 = xv[2] * inv * (1.0f + wv.z);
    const float b1 = xv[3] * inv * (1.0f + wv.w);
    const float o0 = (a0 * cv.x - b0 * sv.x) * oscale;
    const float o1 = (a0 * sv.x + b0 * cv.x) * oscale;
    const float o2 = (a1 * cv.y - b1 * sv.y) * oscale;
    const float o3 = (a1 * sv.y + b1 * cv.y) * oscale;
    uint2 ov;
    ov.x = (unsigned int)f2bf(o0) | ((unsigned int)f2bf(o1) << 16);
    ov.y = (unsigned int)f2bf(o2) | ((unsigned int)f2bf(o3) << 16);
    *(uint2*)(row + 4 * lane) = ov;
  } else {
    __shared__ unsigned short ts[32][264];
    const int g2 = bid - 10240;
    const int b = g2 >> 7, jt = g2 & 127;
    const unsigned short* src = qkv + ((size_t)(b * S_LEN) + jt * 32) * QKV_N + 5 * HD;
#pragma unroll
    for (int it = 0; it < 4; ++it) {
      const int c = tid + 256 * it;
      const int row = c >> 5, col8 = (c & 31) << 3;
      *(uint4*)&ts[row][col8] = *(const uint4*)(src + (size_t)row * QKV_N + col8);
    }
    __syncthreads();
    unsigned short tmp[32];
#pragma unroll
    for (int s2 = 0; s2 < 32; ++s2) {
      const int jj = (s2 >> 1) | ((s2 & 1) << 4);   // inverse of s = 2*(jj&15)|(jj>>4)
      tmp[s2] = ts[jj][tid];
    }
    unsigned short* dst = vtb + ((size_t)(b * 128 + jt) * 256 + tid) * 32;
#pragma unroll
    for (int wq = 0; wq < 4; ++wq) *(uint4*)(dst + wq * 8) = *(uint4*)(tmp + wq * 8);
  }
}

// ---------------------------------------------------------------------------
// Flash-style sliding-window MQA, bf16 MFMA — verified R6 structure (88 VGPR,
// 2 blocks/CU) + T5 s_setprio around MFMA clusters.
//
// T5 mechanism check: 2 independent blocks/CU (no inter-block sync) drift
// through different loop phases -> the CU scheduler has {MFMA-issuing vs
// load-issuing} wave diversity to arbitrate -> setprio applies (m191: +4-7%
// attn with independent blocks; null only in single-block lockstep).
// ---------------------------------------------------------------------------
#define PS_LD 40

__global__ __launch_bounds__(256) void attn_mfma_kernel(
    const unsigned short* __restrict__ qkv, const unsigned short* __restrict__ vtb,
    unsigned short* __restrict__ aob) {
  const int g = blockIdx.x;
  const int xcd = g & 7, slot = g >> 3;      // assume block j -> XCD j%8
  const int h = slot >> 4;                   // 0..3
  const int qt = xcd * 16 + (slot & 15);     // 0..127
  const int b = qt >> 6;
  const int q0 = (qt & 63) << 6;
  const int tid = threadIdx.x;
  const int wave = tid >> 6;
  const int lane = tid & 63;
  const int ln15 = lane & 15;
  const int lgr = lane >> 4;

  __shared__ unsigned short Ks[2][16 * 512];
  __shared__ unsigned short Vts[2][16 * 512];
  __shared__ unsigned short Ps[4][16 * PS_LD];

  const size_t qrow = (size_t)(b * S_LEN + q0 + wave * 16 + ln15) * QKV_N + h * HD;
  s16x8 qfrag[8];
#pragma unroll
  for (int f = 0; f < 8; ++f)
    qfrag[f] = *(const s16x8*)(qkv + qrow + f * 32 + lgr * 8);

  f32x4 acc[16];
#pragma unroll
  for (int t = 0; t < 16; ++t) acc[t] = (f32x4){0.f, 0.f, 0.f, 0.f};
  float l_part[4] = {0.f, 0.f, 0.f, 0.f};

  const int kt_lo = max(0, q0 - WIN) >> 5;
  const int kt_hi = (q0 + 63) >> 5;
  const unsigned short* kbase = qkv + (size_t)(b * S_LEN) * QKV_N + 4 * HD;
  const unsigned short* vbase = vtb + (size_t)b * (S_LEN / 32) * HD * 32;

  auto stage = [&](int kt, int buf) {
#pragma unroll
    for (int u = 0; u < 4; ++u) {
      const int c = wave * 4 + u;
      const int ct = c >> 3, f = c & 7;
      const unsigned short* gk =
          kbase + (size_t)(kt * 32 + ct * 16 + ln15) * QKV_N + f * 32 + lgr * 8;
      gl2lds16(gk, &Ks[buf][c * 512]);
      const unsigned short* gv =
          vbase + (size_t)kt * (HD * 32) + (size_t)(c * 16 + ln15) * 32 + lgr * 8;
      gl2lds16(gv, &Vts[buf][c * 512]);
    }
  };

  stage(kt_lo, 0);
  __syncthreads();

  unsigned short* psw = Ps[wave];
  const int i_row0 = q0 + wave * 16 + lgr * 4;

  for (int kt = kt_lo; kt <= kt_hi; ++kt) {
    const int cur = (kt - kt_lo) & 1;
    if (kt < kt_hi) stage(kt + 1, cur ^ 1);

    // QK^T
    f32x4 sc[2];
    sc[0] = (f32x4){0.f, 0.f, 0.f, 0.f};
    sc[1] = (f32x4){0.f, 0.f, 0.f, 0.f};
    __builtin_amdgcn_s_setprio(1);
#pragma unroll
    for (int f = 0; f < 8; ++f) {
#pragma unroll
      for (int ct = 0; ct < 2; ++ct) {
        const s16x8 kf = *(const s16x8*)&Ks[cur][(ct * 8 + f) * 512 + lane * 8];
        sc[ct] = __builtin_amdgcn_mfma_f32_16x16x32_bf16(qfrag[f], kf, sc[ct], 0, 0, 0);
      }
    }
    __builtin_amdgcn_s_setprio(0);

    // static-max softmax: p = exp(s - 16), masked to 0
    const int j0 = kt * 32 + ln15;
    float p0[4], p1[4];
#pragma unroll
    for (int r = 0; r < 4; ++r) {
      const int i = i_row0 + r;
      const bool a0 = (j0 <= i) && (i - j0 <= WIN);
      const bool a1 = (j0 + 16 <= i) && (i - (j0 + 16) <= WIN);
      const float e0 = __expf(sc[0][r] - 16.0f);
      const float e1 = __expf(sc[1][r] - 16.0f);
      p0[r] = a0 ? e0 : 0.0f;
      p1[r] = a1 ? e1 : 0.0f;
      l_part[r] += p0[r] + p1[r];
    }
    // packed b32 P writes: col 2*ln15 = key ln15 (ct0), col 2*ln15+1 = key 16+ln15
#pragma unroll
    for (int r = 0; r < 4; ++r) {
      const unsigned int pk = (unsigned int)f2bf(p0[r]) | ((unsigned int)f2bf(p1[r]) << 16);
      *(unsigned int*)&psw[(lgr * 4 + r) * PS_LD + (ln15 << 1)] = pk;
    }
    const s16x8 pf = *(const s16x8*)&psw[ln15 * PS_LD + lgr * 8];
    __builtin_amdgcn_s_setprio(1);
#pragma unroll
    for (int t = 0; t < 16; ++t) {
      const s16x8 vf = *(const s16x8*)&Vts[cur][t * 512 + lane * 8];
      acc[t] = __builtin_amdgcn_mfma_f32_16x16x32_bf16(pf, vf, acc[t], 0, 0, 0);
    }
    __builtin_amdgcn_s_setprio(0);
    __syncthreads();
  }

#pragma unroll
  for (int off = 1; off < 16; off <<= 1)
#pragma unroll
    for (int r = 0; r < 4; ++r) l_part[r] += __shfl_xor(l_part[r], off);

  float inv_l[4];
#pragma unroll
  for (int r = 0; r < 4; ++r) inv_l[r] = 1.0f / l_part[r];
#pragma unroll
  for (int t = 0; t < 16; ++t)
#pragma unroll
    for (int r = 0; r < 4; ++r) {
      const size_t orow = (size_t)(b * S_LEN + q0 + wave * 16 + lgr * 4 + r);
      aob[(orow * NH + h) * HD + t * 16 + ln15] = f2bf(acc[t][r] * inv_l[r]);
    }
}

// ---------------------------------------------------------------------------
extern "C" void kernel_launch(void* const* d_in, const int* in_sizes, int n_in,
                              void* d_out, int out_size, void* d_ws, size_t ws_size,
                              hipStream_t stream) {
  const float* x    = (const float*)d_in[0];
  const float* cosb = (const float*)d_in[1];
  const float* sinb = (const float*)d_in[2];
  const float* Wq   = (const float*)d_in[3];
  const float* Wk   = (const float*)d_in[4];
  const float* Wv   = (const float*)d_in[5];
  const float* Wo   = (const float*)d_in[6];
  const float* qw   = (const float*)d_in[7];
  const float* kw   = (const float*)d_in[8];
  float* out = (float*)d_out;

  unsigned short* ws = (unsigned short*)d_ws;
  unsigned short* xb     = ws;                    // 8192*640  = 5242880
  unsigned short* Wqkvt  = xb + 5242880;          // 1536*640  = 983040
  unsigned short* Wot    = Wqkvt + 983040;        // 640*1024  = 655360
  unsigned short* qkvb   = Wot + 655360;          // 8192*1536 = 12582912
  unsigned short* vtb    = qkvb + 12582912;       // 8192*256  = 2097152
  unsigned short* aob    = vtb + 2097152;         // 8192*1024 = 8388608
  const int M = 2 * S_LEN;

  prep_kernel<<<5520, 256, 0, stream>>>(x, xb, Wq, Wk, Wv, Wo, Wqkvt, Wot);
  gemm_bt<true><<<dim3(QKV_N / 128, M / 128), 256, 0, stream>>>(xb, Wqkvt, qkvb, M, QKV_N, 640);
  normrope_vt_kernel<<<10240 + 256, 256, 0, stream>>>(qkvb, cosb, sinb, qw, kw, vtb);
  attn_mfma_kernel<<<M / 64 * NH, 256, 0, stream>>>(qkvb, vtb, aob);
  gemm_bt64<<<dim3(640 / 128, M / 64), 256, 0, stream>>>(aob, Wot, out, M, 640, 1024);
}

// Round 12
// 193.122 us; speedup vs baseline: 1.1667x; 1.0249x over previous
//
#include <hip/hip_runtime.h>
#include <hip/hip_bf16.h>

#define S_LEN 4096
#define NH 4
#define HD 256
#define WIN 512
#define ATT_SCALE 0.0625f   // 256^-0.5
#define QKV_N 1536          // packed q(1024) | k(256) | v(256)

typedef short s16x8 __attribute__((ext_vector_type(8)));
typedef float f32x4 __attribute__((ext_vector_type(4)));

static __device__ inline unsigned short f2bf(float f) {
  union { float f; unsigned int u; } v; v.f = f;
  unsigned int r = v.u + 0x7fff + ((v.u >> 16) & 1);   // RNE
  return (unsigned short)(r >> 16);
}
static __device__ inline float bf2f(unsigned short h) {
  union { unsigned int u; float f; } v; v.u = ((unsigned int)h) << 16;
  return v.f;
}
static __device__ inline void gl2lds16(const void* g, void* l) {
  __builtin_amdgcn_global_load_lds(
      (const __attribute__((address_space(1))) unsigned int*)g,
      (__attribute__((address_space(3))) unsigned int*)l, 16, 0, 0);
}

// ---------------------------------------------------------------------------
// Fused prep: region [0,5120) = x fp32->bf16 cast; then 4 transpose+cast
// weight regions (Wq,Wk,Wv -> packed Wqkvt; Wo -> Wot). One dispatch.
// ---------------------------------------------------------------------------
static __device__ void trcast_tile(const float* __restrict__ src,
                                   unsigned short* __restrict__ dst,
                                   int K, int N, int bn, int bk, int tid,
                                   float* ts /*[64][65]*/) {
#pragma unroll
  for (int it = 0; it < 4; ++it) {
    const int c = it * 256 + tid;
    const int row = c >> 4, col4 = (c & 15) << 2;
    const float4 v = *(const float4*)(src + (size_t)(bk * 64 + row) * N + bn * 64 + col4);
    ts[row * 65 + col4 + 0] = v.x; ts[row * 65 + col4 + 1] = v.y;
    ts[row * 65 + col4 + 2] = v.z; ts[row * 65 + col4 + 3] = v.w;
  }
  __syncthreads();
#pragma unroll
  for (int it = 0; it < 4; ++it) {
    const int c = it * 256 + tid;
    const int nrow = c >> 4, kc4 = (c & 15) << 2;
    const unsigned int p0 = f2bf(ts[(kc4 + 0) * 65 + nrow]) | ((unsigned int)f2bf(ts[(kc4 + 1) * 65 + nrow]) << 16);
    const unsigned int p1 = f2bf(ts[(kc4 + 2) * 65 + nrow]) | ((unsigned int)f2bf(ts[(kc4 + 3) * 65 + nrow]) << 16);
    *(uint2*)(dst + (size_t)(bn * 64 + nrow) * K + bk * 64 + kc4) = make_uint2(p0, p1);
  }
}

__global__ __launch_bounds__(256) void prep_kernel(
    const float* __restrict__ x, unsigned short* __restrict__ xb,
    const float* __restrict__ Wq, const float* __restrict__ Wk,
    const float* __restrict__ Wv, const float* __restrict__ Wo,
    unsigned short* __restrict__ Wqkvt, unsigned short* __restrict__ Wot) {
  __shared__ float ts[64 * 65];
  const int g = blockIdx.x;
  const int tid = threadIdx.x;
  if (g < 5120) {                    // cvt x -> bf16 (1310720 float4 elems)
    const int t = g * 256 + tid;
    const float4 v = ((const float4*)x)[t];
    const unsigned int p0 = f2bf(v.x) | ((unsigned int)f2bf(v.y) << 16);
    const unsigned int p1 = f2bf(v.z) | ((unsigned int)f2bf(v.w) << 16);
    *(uint2*)(xb + (size_t)t * 4) = make_uint2(p0, p1);
  } else if (g < 5280) {             // Wq: N=1024 (16), K=640 (10)
    const int g2 = g - 5120;
    trcast_tile(Wq, Wqkvt, 640, 1024, g2 & 15, g2 >> 4, tid, ts);
  } else if (g < 5320) {             // Wk: N=256 (4), K=640 (10)
    const int g2 = g - 5280;
    trcast_tile(Wk, Wqkvt + (size_t)1024 * 640, 640, 256, g2 & 3, g2 >> 2, tid, ts);
  } else if (g < 5360) {             // Wv
    const int g2 = g - 5320;
    trcast_tile(Wv, Wqkvt + (size_t)1280 * 640, 640, 256, g2 & 3, g2 >> 2, tid, ts);
  } else {                           // Wo: N=640 (10), K=1024 (16)
    const int g2 = g - 5360;
    trcast_tile(Wo, Wot, 1024, 640, g2 % 10, g2 / 10, tid, ts);
  }
}

// ---------------------------------------------------------------------------
// bf16 MFMA GEMM (m97 structure): C[M,N] = A[M,K] @ Bt[N,K]^T. 128x128 tile.
// T1 XCD swizzle: 12 blocks sharing an A-panel (164KB) were landing on
// different XCDs (round-robin on linear id) -> A fetched ~8x from HBM
// (10.5 -> ~84 MB). Bijective remap (768%8==0): XCD k gets bm in
// [k*8,k*8+8) x all bn -> per-XCD A working set 1.3MB (L2-resident),
// fetched once.
// ---------------------------------------------------------------------------
template <bool BF16OUT>
__global__ __launch_bounds__(256) void gemm_bt(const unsigned short* __restrict__ A,
                                               const unsigned short* __restrict__ Bt,
                                               void* __restrict__ Cv,
                                               int M, int N, int K) {
  __shared__ unsigned short As[128 * 32];
  __shared__ unsigned short Bs[128 * 32];
  const int tid = threadIdx.x;
  const int wave = tid >> 6, lane = tid & 63;
  const int ln15 = lane & 15, lgr = lane >> 4;
  const int nbn = gridDim.x;
  const int lin = blockIdx.y * nbn + blockIdx.x;
  const int cpx = (gridDim.x * gridDim.y) >> 3;   // blocks per XCD
  const int swz = (lin & 7) * cpx + (lin >> 3);   // bijective when nwg%8==0
  const int bm = swz / nbn, bn = swz % nbn;
  const int wr = wave & 1, wc = wave >> 1;
  const unsigned short* Ab = A + (size_t)bm * 128 * K;
  const unsigned short* Bb = Bt + (size_t)bn * 128 * K;

  f32x4 acc[4][4];
#pragma unroll
  for (int mt = 0; mt < 4; ++mt)
#pragma unroll
    for (int nt = 0; nt < 4; ++nt) acc[mt][nt] = (f32x4){0.f, 0.f, 0.f, 0.f};

  for (int kt = 0; kt < K; kt += 32) {
#pragma unroll
    for (int i = 0; i < 2; ++i) {
      const int c = tid + 256 * i;
      const int row = c >> 2, kc = (c & 3) << 3;
      gl2lds16(Ab + (size_t)row * K + kt + kc, &As[c * 8]);
      gl2lds16(Bb + (size_t)row * K + kt + kc, &Bs[c * 8]);
    }
    __syncthreads();
    s16x8 af[4], bfr[4];
#pragma unroll
    for (int t = 0; t < 4; ++t) {
      af[t]  = *(const s16x8*)&As[(wr * 64 + t * 16 + ln15) * 32 + lgr * 8];
      bfr[t] = *(const s16x8*)&Bs[(wc * 64 + t * 16 + ln15) * 32 + lgr * 8];
    }
#pragma unroll
    for (int mt = 0; mt < 4; ++mt)
#pragma unroll
      for (int nt = 0; nt < 4; ++nt)
        acc[mt][nt] = __builtin_amdgcn_mfma_f32_16x16x32_bf16(af[mt], bfr[nt], acc[mt][nt], 0, 0, 0);
    __syncthreads();
  }

#pragma unroll
  for (int mt = 0; mt < 4; ++mt)
#pragma unroll
    for (int nt = 0; nt < 4; ++nt)
#pragma unroll
      for (int r = 0; r < 4; ++r) {
        const size_t row = bm * 128 + wr * 64 + mt * 16 + lgr * 4 + r;
        const size_t col = bn * 128 + wc * 64 + nt * 16 + ln15;
        if (BF16OUT) ((unsigned short*)Cv)[row * N + col] = f2bf(acc[mt][nt][r]);
        else         ((float*)Cv)[row * N + col] = acc[mt][nt][r];
      }
}

// ---------------------------------------------------------------------------
// 64x128-tile variant (fp32 out) for the output projection: N=640 -> 5 n-tiles,
// grid 128x5 = 640 blocks. T1 XCD swizzle (640%8==0): the 5 blocks sharing an
// aob-panel (131KB) were landing on 5 XCDs -> A fetched ~5x (16.8 -> ~84 MB).
// Remap gives XCD k bm in [k*16,k*16+16) x all bn -> per-XCD A 2.1MB, once.
// ---------------------------------------------------------------------------
__global__ __launch_bounds__(256) void gemm_bt64(const unsigned short* __restrict__ A,
                                                 const unsigned short* __restrict__ Bt,
                                                 float* __restrict__ C,
                                                 int M, int N, int K) {
  __shared__ unsigned short As[64 * 32];
  __shared__ unsigned short Bs[128 * 32];
  const int tid = threadIdx.x;
  const int wave = tid >> 6, lane = tid & 63;
  const int ln15 = lane & 15, lgr = lane >> 4;
  const int nbn = gridDim.x;
  const int lin = blockIdx.y * nbn + blockIdx.x;
  const int cpx = (gridDim.x * gridDim.y) >> 3;
  const int swz = (lin & 7) * cpx + (lin >> 3);
  const int bm = swz / nbn, bn = swz % nbn;
  const unsigned short* Ab = A + (size_t)bm * 64 * K;
  const unsigned short* Bb = Bt + (size_t)bn * 128 * K;

  f32x4 acc[4][2];
#pragma unroll
  for (int mt = 0; mt < 4; ++mt)
#pragma unroll
    for (int nt = 0; nt < 2; ++nt) acc[mt][nt] = (f32x4){0.f, 0.f, 0.f, 0.f};

  for (int kt = 0; kt < K; kt += 32) {
    {
      const int row = tid >> 2, kc = (tid & 3) << 3;
      gl2lds16(Ab + (size_t)row * K + kt + kc, &As[tid * 8]);
#pragma unroll
      for (int i = 0; i < 2; ++i) {
        const int c = tid + 256 * i;
        const int brow = c >> 2, bkc = (c & 3) << 3;
        gl2lds16(Bb + (size_t)brow * K + kt + bkc, &Bs[c * 8]);
      }
    }
    __syncthreads();
    s16x8 af[4], bfr[2];
#pragma unroll
    for (int t = 0; t < 4; ++t)
      af[t] = *(const s16x8*)&As[(t * 16 + ln15) * 32 + lgr * 8];
#pragma unroll
    for (int t = 0; t < 2; ++t)
      bfr[t] = *(const s16x8*)&Bs[(wave * 32 + t * 16 + ln15) * 32 + lgr * 8];
#pragma unroll
    for (int mt = 0; mt < 4; ++mt)
#pragma unroll
      for (int nt = 0; nt < 2; ++nt)
        acc[mt][nt] = __builtin_amdgcn_mfma_f32_16x16x32_bf16(af[mt], bfr[nt], acc[mt][nt], 0, 0, 0);
    __syncthreads();
  }

#pragma unroll
  for (int mt = 0; mt < 4; ++mt)
#pragma unroll
    for (int nt = 0; nt < 2; ++nt)
#pragma unroll
      for (int r = 0; r < 4; ++r) {
        const size_t row = bm * 64 + mt * 16 + lgr * 4 + r;
        const size_t col = bn * 128 + wave * 32 + nt * 16 + ln15;
        C[row * N + col] = acc[mt][nt][r];
      }
}

// ---------------------------------------------------------------------------
// Fused RMSNorm+RoPE (blocks [0,10240)) + V-transpose (blocks [10240,10496)).
// (R6 verified config: Q-fusion into attn abandoned after two VGPR-cliff
// regressions, R8/R10.)
//
// Norm part wave-per-row: one wave = one 256-elem row, 4 elems/lane via uint2,
// wave-local shfl reduce only -- zero barriers, zero LDS, 4 rows per block.
//
// V-transpose uses INTERLEAVED key storage order s = 2*(jj&15) | (jj>>4), so
// attention's P round-trip can write packed b32 pairs (PV is key-permutation
// invariant as long as P cols and Vt cols share the order).
// ---------------------------------------------------------------------------
__global__ __launch_bounds__(256) void normrope_vt_kernel(
    unsigned short* __restrict__ qkv,
    const float* __restrict__ cosb, const float* __restrict__ sinb,
    const float* __restrict__ qw, const float* __restrict__ kw,
    unsigned short* __restrict__ vtb) {
  const int bid = blockIdx.x;
  const int tid = threadIdx.x;
  if (bid < 10240) {
    const int lane = tid & 63, wave = tid >> 6;
    const int idx = bid * 4 + wave;          // 0..40959 (row id)
    const int h = idx % 5;
    const int bs = idx / 5;
    const int s = bs & (S_LEN - 1);
    unsigned short* base = qkv + (size_t)bs * QKV_N;
    unsigned short* row; const float* w; float oscale;
    if (h < 4) { row = base + h * HD;  w = qw; oscale = ATT_SCALE; }
    else       { row = base + 4 * HD;  w = kw; oscale = 1.0f; }
    // lane handles elements [4*lane, 4*lane+4) = rope pairs pi=2*lane, 2*lane+1
    const uint2 pv = *(const uint2*)(row + 4 * lane);
    float xv[4];
    xv[0] = bf2f((unsigned short)(pv.x & 0xffff));
    xv[1] = bf2f((unsigned short)(pv.x >> 16));
    xv[2] = bf2f((unsigned short)(pv.y & 0xffff));
    xv[3] = bf2f((unsigned short)(pv.y >> 16));
    float ssq = xv[0] * xv[0] + xv[1] * xv[1] + xv[2] * xv[2] + xv[3] * xv[3];
#pragma unroll
    for (int off = 32; off > 0; off >>= 1) ssq += __shfl_xor(ssq, off);
    const float inv = rsqrtf(ssq * (1.0f / 256.0f) + 1e-6f);
    const float4 wv = *(const float4*)(w + 4 * lane);
    const float2 cv = *(const float2*)(cosb + (size_t)s * (HD / 2) + 2 * lane);
    const float2 sv = *(const float2*)(sinb + (size_t)s * (HD / 2) + 2 * lane);
    const float a0 = xv[0] * inv * (1.0f + wv.x);
    const float b0 = xv[1] * inv * (1.0f + wv.y);
    const float a1 = xv[2] * inv * (1.0f + wv.z);
    const float b1 = xv[3] * inv * (1.0f + wv.w);
    const float o0 = (a0 * cv.x - b0 * sv.x) * oscale;
    const float o1 = (a0 * sv.x + b0 * cv.x) * oscale;
    const float o2 = (a1 * cv.y - b1 * sv.y) * oscale;
    const float o3 = (a1 * sv.y + b1 * cv.y) * oscale;
    uint2 ov;
    ov.x = (unsigned int)f2bf(o0) | ((unsigned int)f2bf(o1) << 16);
    ov.y = (unsigned int)f2bf(o2) | ((unsigned int)f2bf(o3) << 16);
    *(uint2*)(row + 4 * lane) = ov;
  } else {
    __shared__ unsigned short ts[32][264];
    const int g2 = bid - 10240;
    const int b = g2 >> 7, jt = g2 & 127;
    const unsigned short* src = qkv + ((size_t)(b * S_LEN) + jt * 32) * QKV_N + 5 * HD;
#pragma unroll
    for (int it = 0; it < 4; ++it) {
      const int c = tid + 256 * it;
      const int row = c >> 5, col8 = (c & 31) << 3;
      *(uint4*)&ts[row][col8] = *(const uint4*)(src + (size_t)row * QKV_N + col8);
    }
    __syncthreads();
    unsigned short tmp[32];
#pragma unroll
    for (int s2 = 0; s2 < 32; ++s2) {
      const int jj = (s2 >> 1) | ((s2 & 1) << 4);   // inverse of s = 2*(jj&15)|(jj>>4)
      tmp[s2] = ts[jj][tid];
    }
    unsigned short* dst = vtb + ((size_t)(b * 128 + jt) * 256 + tid) * 32;
#pragma unroll
    for (int wq = 0; wq < 4; ++wq) *(uint4*)(dst + wq * 8) = *(uint4*)(tmp + wq * 8);
  }
}

// ---------------------------------------------------------------------------
// Flash-style sliding-window MQA, bf16 MFMA — verified R6 structure (88 VGPR,
// 2 blocks/CU) + T5 s_setprio around MFMA clusters (within noise, kept).
// ---------------------------------------------------------------------------
#define PS_LD 40

__global__ __launch_bounds__(256) void attn_mfma_kernel(
    const unsigned short* __restrict__ qkv, const unsigned short* __restrict__ vtb,
    unsigned short* __restrict__ aob) {
  const int g = blockIdx.x;
  const int xcd = g & 7, slot = g >> 3;      // assume block j -> XCD j%8
  const int h = slot >> 4;                   // 0..3
  const int qt = xcd * 16 + (slot & 15);     // 0..127
  const int b = qt >> 6;
  const int q0 = (qt & 63) << 6;
  const int tid = threadIdx.x;
  const int wave = tid >> 6;
  const int lane = tid & 63;
  const int ln15 = lane & 15;
  const int lgr = lane >> 4;

  __shared__ unsigned short Ks[2][16 * 512];
  __shared__ unsigned short Vts[2][16 * 512];
  __shared__ unsigned short Ps[4][16 * PS_LD];

  const size_t qrow = (size_t)(b * S_LEN + q0 + wave * 16 + ln15) * QKV_N + h * HD;
  s16x8 qfrag[8];
#pragma unroll
  for (int f = 0; f < 8; ++f)
    qfrag[f] = *(const s16x8*)(qkv + qrow + f * 32 + lgr * 8);

  f32x4 acc[16];
#pragma unroll
  for (int t = 0; t < 16; ++t) acc[t] = (f32x4){0.f, 0.f, 0.f, 0.f};
  float l_part[4] = {0.f, 0.f, 0.f, 0.f};

  const int kt_lo = max(0, q0 - WIN) >> 5;
  const int kt_hi = (q0 + 63) >> 5;
  const unsigned short* kbase = qkv + (size_t)(b * S_LEN) * QKV_N + 4 * HD;
  const unsigned short* vbase = vtb + (size_t)b * (S_LEN / 32) * HD * 32;

  auto stage = [&](int kt, int buf) {
#pragma unroll
    for (int u = 0; u < 4; ++u) {
      const int c = wave * 4 + u;
      const int ct = c >> 3, f = c & 7;
      const unsigned short* gk =
          kbase + (size_t)(kt * 32 + ct * 16 + ln15) * QKV_N + f * 32 + lgr * 8;
      gl2lds16(gk, &Ks[buf][c * 512]);
      const unsigned short* gv =
          vbase + (size_t)kt * (HD * 32) + (size_t)(c * 16 + ln15) * 32 + lgr * 8;
      gl2lds16(gv, &Vts[buf][c * 512]);
    }
  };

  stage(kt_lo, 0);
  __syncthreads();

  unsigned short* psw = Ps[wave];
  const int i_row0 = q0 + wave * 16 + lgr * 4;

  for (int kt = kt_lo; kt <= kt_hi; ++kt) {
    const int cur = (kt - kt_lo) & 1;
    if (kt < kt_hi) stage(kt + 1, cur ^ 1);

    // QK^T
    f32x4 sc[2];
    sc[0] = (f32x4){0.f, 0.f, 0.f, 0.f};
    sc[1] = (f32x4){0.f, 0.f, 0.f, 0.f};
    __builtin_amdgcn_s_setprio(1);
#pragma unroll
    for (int f = 0; f < 8; ++f) {
#pragma unroll
      for (int ct = 0; ct < 2; ++ct) {
        const s16x8 kf = *(const s16x8*)&Ks[cur][(ct * 8 + f) * 512 + lane * 8];
        sc[ct] = __builtin_amdgcn_mfma_f32_16x16x32_bf16(qfrag[f], kf, sc[ct], 0, 0, 0);
      }
    }
    __builtin_amdgcn_s_setprio(0);

    // static-max softmax: p = exp(s - 16), masked to 0
    const int j0 = kt * 32 + ln15;
    float p0[4], p1[4];
#pragma unroll
    for (int r = 0; r < 4; ++r) {
      const int i = i_row0 + r;
      const bool a0 = (j0 <= i) && (i - j0 <= WIN);
      const bool a1 = (j0 + 16 <= i) && (i - (j0 + 16) <= WIN);
      const float e0 = __expf(sc[0][r] - 16.0f);
      const float e1 = __expf(sc[1][r] - 16.0f);
      p0[r] = a0 ? e0 : 0.0f;
      p1[r] = a1 ? e1 : 0.0f;
      l_part[r] += p0[r] + p1[r];
    }
    // packed b32 P writes: col 2*ln15 = key ln15 (ct0), col 2*ln15+1 = key 16+ln15
#pragma unroll
    for (int r = 0; r < 4; ++r) {
      const unsigned int pk = (unsigned int)f2bf(p0[r]) | ((unsigned int)f2bf(p1[r]) << 16);
      *(unsigned int*)&psw[(lgr * 4 + r) * PS_LD + (ln15 << 1)] = pk;
    }
    const s16x8 pf = *(const s16x8*)&psw[ln15 * PS_LD + lgr * 8];
    __builtin_amdgcn_s_setprio(1);
#pragma unroll
    for (int t = 0; t < 16; ++t) {
      const s16x8 vf = *(const s16x8*)&Vts[cur][t * 512 + lane * 8];
      acc[t] = __builtin_amdgcn_mfma_f32_16x16x32_bf16(pf, vf, acc[t], 0, 0, 0);
    }
    __builtin_amdgcn_s_setprio(0);
    __syncthreads();
  }

#pragma unroll
  for (int off = 1; off < 16; off <<= 1)
#pragma unroll
    for (int r = 0; r < 4; ++r) l_part[r] += __shfl_xor(l_part[r], off);

  float inv_l[4];
#pragma unroll
  for (int r = 0; r < 4; ++r) inv_l[r] = 1.0f / l_part[r];
#pragma unroll
  for (int t = 0; t < 16; ++t)
#pragma unroll
    for (int r = 0; r < 4; ++r) {
      const size_t orow = (size_t)(b * S_LEN + q0 + wave * 16 + lgr * 4 + r);
      aob[(orow * NH + h) * HD + t * 16 + ln15] = f2bf(acc[t][r] * inv_l[r]);
    }
}

// ---------------------------------------------------------------------------
extern "C" void kernel_launch(void* const* d_in, const int* in_sizes, int n_in,
                              void* d_out, int out_size, void* d_ws, size_t ws_size,
                              hipStream_t stream) {
  const float* x    = (const float*)d_in[0];
  const float* cosb = (const float*)d_in[1];
  const float* sinb = (const float*)d_in[2];
  const float* Wq   = (const float*)d_in[3];
  const float* Wk   = (const float*)d_in[4];
  const float* Wv   = (const float*)d_in[5];
  const float* Wo   = (const float*)d_in[6];
  const float* qw   = (const float*)d_in[7];
  const float* kw   = (const float*)d_in[8];
  float* out = (float*)d_out;

  unsigned short* ws = (unsigned short*)d_ws;
  unsigned short* xb     = ws;                    // 8192*640  = 5242880
  unsigned short* Wqkvt  = xb + 5242880;          // 1536*640  = 983040
  unsigned short* Wot    = Wqkvt + 983040;        // 640*1024  = 655360
  unsigned short* qkvb   = Wot + 655360;          // 8192*1536 = 12582912
  unsigned short* vtb    = qkvb + 12582912;       // 8192*256  = 2097152
  unsigned short* aob    = vtb + 2097152;         // 8192*1024 = 8388608
  const int M = 2 * S_LEN;

  prep_kernel<<<5520, 256, 0, stream>>>(x, xb, Wq, Wk, Wv, Wo, Wqkvt, Wot);
  gemm_bt<true><<<dim3(QKV_N / 128, M / 128), 256, 0, stream>>>(xb, Wqkvt, qkvb, M, QKV_N, 640);
  normrope_vt_kernel<<<10240 + 256, 256, 0, stream>>>(qkvb, cosb, sinb, qw, kw, vtb);
  attn_mfma_kernel<<<M / 64 * NH, 256, 0, stream>>>(qkvb, vtb, aob);
  gemm_bt64<<<dim3(640 / 128, M / 64), 256, 0, stream>>>(aob, Wot, out, M, 640, 1024);
}

// Round 13
// 187.237 us; speedup vs baseline: 1.2034x; 1.0314x over previous
//
#include <hip/hip_runtime.h>
#include <hip/hip_bf16.h>

#define S_LEN 4096
#define NH 4
#define HD 256
#define WIN 512
#define ATT_SCALE 0.0625f   // 256^-0.5
#define QKV_N 1536          // packed q(1024) | k(256) | v(256)

typedef short s16x8 __attribute__((ext_vector_type(8)));
typedef float f32x4 __attribute__((ext_vector_type(4)));

static __device__ inline unsigned short f2bf(float f) {
  union { float f; unsigned int u; } v; v.f = f;
  unsigned int r = v.u + 0x7fff + ((v.u >> 16) & 1);   // RNE
  return (unsigned short)(r >> 16);
}
static __device__ inline float bf2f(unsigned short h) {
  union { unsigned int u; float f; } v; v.u = ((unsigned int)h) << 16;
  return v.f;
}
static __device__ inline void gl2lds16(const void* g, void* l) {
  __builtin_amdgcn_global_load_lds(
      (const __attribute__((address_space(1))) unsigned int*)g,
      (__attribute__((address_space(3))) unsigned int*)l, 16, 0, 0);
}

// ---------------------------------------------------------------------------
// Fused prep: region [0,5120) = x fp32->bf16 cast; then 4 transpose+cast
// weight regions (Wq,Wk,Wv -> packed Wqkvt; Wo -> Wot). One dispatch.
// ---------------------------------------------------------------------------
static __device__ void trcast_tile(const float* __restrict__ src,
                                   unsigned short* __restrict__ dst,
                                   int K, int N, int bn, int bk, int tid,
                                   float* ts /*[64][65]*/) {
#pragma unroll
  for (int it = 0; it < 4; ++it) {
    const int c = it * 256 + tid;
    const int row = c >> 4, col4 = (c & 15) << 2;
    const float4 v = *(const float4*)(src + (size_t)(bk * 64 + row) * N + bn * 64 + col4);
    ts[row * 65 + col4 + 0] = v.x; ts[row * 65 + col4 + 1] = v.y;
    ts[row * 65 + col4 + 2] = v.z; ts[row * 65 + col4 + 3] = v.w;
  }
  __syncthreads();
#pragma unroll
  for (int it = 0; it < 4; ++it) {
    const int c = it * 256 + tid;
    const int nrow = c >> 4, kc4 = (c & 15) << 2;
    const unsigned int p0 = f2bf(ts[(kc4 + 0) * 65 + nrow]) | ((unsigned int)f2bf(ts[(kc4 + 1) * 65 + nrow]) << 16);
    const unsigned int p1 = f2bf(ts[(kc4 + 2) * 65 + nrow]) | ((unsigned int)f2bf(ts[(kc4 + 3) * 65 + nrow]) << 16);
    *(uint2*)(dst + (size_t)(bn * 64 + nrow) * K + bk * 64 + kc4) = make_uint2(p0, p1);
  }
}

__global__ __launch_bounds__(256) void prep_kernel(
    const float* __restrict__ x, unsigned short* __restrict__ xb,
    const float* __restrict__ Wq, const float* __restrict__ Wk,
    const float* __restrict__ Wv, const float* __restrict__ Wo,
    unsigned short* __restrict__ Wqkvt, unsigned short* __restrict__ Wot) {
  __shared__ float ts[64 * 65];
  const int g = blockIdx.x;
  const int tid = threadIdx.x;
  if (g < 5120) {                    // cvt x -> bf16 (1310720 float4 elems)
    const int t = g * 256 + tid;
    const float4 v = ((const float4*)x)[t];
    const unsigned int p0 = f2bf(v.x) | ((unsigned int)f2bf(v.y) << 16);
    const unsigned int p1 = f2bf(v.z) | ((unsigned int)f2bf(v.w) << 16);
    *(uint2*)(xb + (size_t)t * 4) = make_uint2(p0, p1);
  } else if (g < 5280) {             // Wq: N=1024 (16), K=640 (10)
    const int g2 = g - 5120;
    trcast_tile(Wq, Wqkvt, 640, 1024, g2 & 15, g2 >> 4, tid, ts);
  } else if (g < 5320) {             // Wk: N=256 (4), K=640 (10)
    const int g2 = g - 5280;
    trcast_tile(Wk, Wqkvt + (size_t)1024 * 640, 640, 256, g2 & 3, g2 >> 2, tid, ts);
  } else if (g < 5360) {             // Wv
    const int g2 = g - 5320;
    trcast_tile(Wv, Wqkvt + (size_t)1280 * 640, 640, 256, g2 & 3, g2 >> 2, tid, ts);
  } else {                           // Wo: N=640 (10), K=1024 (16)
    const int g2 = g - 5360;
    trcast_tile(Wo, Wot, 1024, 640, g2 % 10, g2 / 10, tid, ts);
  }
}

// ---------------------------------------------------------------------------
// bf16 MFMA GEMM (m97 structure + BK=64 slab staging): C = A @ Bt^T, 128x128.
// BK=64 as TWO independent [128][32] slabs: each slab keeps the proven LDS
// layout / fragment-read pattern (gl2lds dest must stay linear, m104; a
// [128][64] tile would be a 16-way bank conflict, m201). Halves the
// per-K-step barrier+vmcnt(0)-drain count (the m97 ~20% stall): 40 -> 20
// barriers at K=640.
// T1 XCD swizzle: bijective remap (nwg%8==0) so the 12 blocks sharing an
// A-panel land on one XCD's L2.
// ---------------------------------------------------------------------------
template <bool BF16OUT>
__global__ __launch_bounds__(256) void gemm_bt(const unsigned short* __restrict__ A,
                                               const unsigned short* __restrict__ Bt,
                                               void* __restrict__ Cv,
                                               int M, int N, int K) {
  __shared__ unsigned short As[2][128 * 32];
  __shared__ unsigned short Bs[2][128 * 32];
  const int tid = threadIdx.x;
  const int wave = tid >> 6, lane = tid & 63;
  const int ln15 = lane & 15, lgr = lane >> 4;
  const int nbn = gridDim.x;
  const int lin = blockIdx.y * nbn + blockIdx.x;
  const int cpx = (gridDim.x * gridDim.y) >> 3;   // blocks per XCD
  const int swz = (lin & 7) * cpx + (lin >> 3);   // bijective when nwg%8==0
  const int bm = swz / nbn, bn = swz % nbn;
  const int wr = wave & 1, wc = wave >> 1;
  const unsigned short* Ab = A + (size_t)bm * 128 * K;
  const unsigned short* Bb = Bt + (size_t)bn * 128 * K;

  f32x4 acc[4][4];
#pragma unroll
  for (int mt = 0; mt < 4; ++mt)
#pragma unroll
    for (int nt = 0; nt < 4; ++nt) acc[mt][nt] = (f32x4){0.f, 0.f, 0.f, 0.f};

  for (int kt = 0; kt < K; kt += 64) {
#pragma unroll
    for (int s = 0; s < 2; ++s)
#pragma unroll
      for (int i = 0; i < 2; ++i) {
        const int c = tid + 256 * i;
        const int row = c >> 2, kc = (c & 3) << 3;
        gl2lds16(Ab + (size_t)row * K + kt + s * 32 + kc, &As[s][c * 8]);
        gl2lds16(Bb + (size_t)row * K + kt + s * 32 + kc, &Bs[s][c * 8]);
      }
    __syncthreads();
#pragma unroll
    for (int s = 0; s < 2; ++s) {
      s16x8 af[4], bfr[4];
#pragma unroll
      for (int t = 0; t < 4; ++t) {
        af[t]  = *(const s16x8*)&As[s][(wr * 64 + t * 16 + ln15) * 32 + lgr * 8];
        bfr[t] = *(const s16x8*)&Bs[s][(wc * 64 + t * 16 + ln15) * 32 + lgr * 8];
      }
#pragma unroll
      for (int mt = 0; mt < 4; ++mt)
#pragma unroll
        for (int nt = 0; nt < 4; ++nt)
          acc[mt][nt] = __builtin_amdgcn_mfma_f32_16x16x32_bf16(af[mt], bfr[nt], acc[mt][nt], 0, 0, 0);
    }
    __syncthreads();
  }

#pragma unroll
  for (int mt = 0; mt < 4; ++mt)
#pragma unroll
    for (int nt = 0; nt < 4; ++nt)
#pragma unroll
      for (int r = 0; r < 4; ++r) {
        const size_t row = bm * 128 + wr * 64 + mt * 16 + lgr * 4 + r;
        const size_t col = bn * 128 + wc * 64 + nt * 16 + ln15;
        if (BF16OUT) ((unsigned short*)Cv)[row * N + col] = f2bf(acc[mt][nt][r]);
        else         ((float*)Cv)[row * N + col] = acc[mt][nt][r];
      }
}

// ---------------------------------------------------------------------------
// 64x128-tile variant (fp32 out) for the output projection, BK=64 slabs:
// barriers 64 -> 32 at K=1024. Grid 128x5 = 640 blocks, XCD-swizzled.
// ---------------------------------------------------------------------------
__global__ __launch_bounds__(256) void gemm_bt64(const unsigned short* __restrict__ A,
                                                 const unsigned short* __restrict__ Bt,
                                                 float* __restrict__ C,
                                                 int M, int N, int K) {
  __shared__ unsigned short As[2][64 * 32];
  __shared__ unsigned short Bs[2][128 * 32];
  const int tid = threadIdx.x;
  const int wave = tid >> 6, lane = tid & 63;
  const int ln15 = lane & 15, lgr = lane >> 4;
  const int nbn = gridDim.x;
  const int lin = blockIdx.y * nbn + blockIdx.x;
  const int cpx = (gridDim.x * gridDim.y) >> 3;
  const int swz = (lin & 7) * cpx + (lin >> 3);
  const int bm = swz / nbn, bn = swz % nbn;
  const unsigned short* Ab = A + (size_t)bm * 64 * K;
  const unsigned short* Bb = Bt + (size_t)bn * 128 * K;

  f32x4 acc[4][2];
#pragma unroll
  for (int mt = 0; mt < 4; ++mt)
#pragma unroll
    for (int nt = 0; nt < 2; ++nt) acc[mt][nt] = (f32x4){0.f, 0.f, 0.f, 0.f};

  for (int kt = 0; kt < K; kt += 64) {
#pragma unroll
    for (int s = 0; s < 2; ++s) {
      const int row = tid >> 2, kc = (tid & 3) << 3;
      gl2lds16(Ab + (size_t)row * K + kt + s * 32 + kc, &As[s][tid * 8]);
#pragma unroll
      for (int i = 0; i < 2; ++i) {
        const int c = tid + 256 * i;
        const int brow = c >> 2, bkc = (c & 3) << 3;
        gl2lds16(Bb + (size_t)brow * K + kt + s * 32 + bkc, &Bs[s][c * 8]);
      }
    }
    __syncthreads();
#pragma unroll
    for (int s = 0; s < 2; ++s) {
      s16x8 af[4], bfr[2];
#pragma unroll
      for (int t = 0; t < 4; ++t)
        af[t] = *(const s16x8*)&As[s][(t * 16 + ln15) * 32 + lgr * 8];
#pragma unroll
      for (int t = 0; t < 2; ++t)
        bfr[t] = *(const s16x8*)&Bs[s][(wave * 32 + t * 16 + ln15) * 32 + lgr * 8];
#pragma unroll
      for (int mt = 0; mt < 4; ++mt)
#pragma unroll
        for (int nt = 0; nt < 2; ++nt)
          acc[mt][nt] = __builtin_amdgcn_mfma_f32_16x16x32_bf16(af[mt], bfr[nt], acc[mt][nt], 0, 0, 0);
    }
    __syncthreads();
  }

#pragma unroll
  for (int mt = 0; mt < 4; ++mt)
#pragma unroll
    for (int nt = 0; nt < 2; ++nt)
#pragma unroll
      for (int r = 0; r < 4; ++r) {
        const size_t row = bm * 64 + mt * 16 + lgr * 4 + r;
        const size_t col = bn * 128 + wave * 32 + nt * 16 + ln15;
        C[row * N + col] = acc[mt][nt][r];
      }
}

// ---------------------------------------------------------------------------
// Fused RMSNorm+RoPE (blocks [0,10240)) + V-transpose (blocks [10240,10496)).
// (R6 verified config: Q-fusion into attn abandoned after two VGPR-cliff
// regressions, R8/R10.)
//
// Norm part wave-per-row: one wave = one 256-elem row, 4 elems/lane via uint2,
// wave-local shfl reduce only -- zero barriers, zero LDS, 4 rows per block.
//
// V-transpose uses INTERLEAVED key storage order s = 2*(jj&15) | (jj>>4), so
// attention's P round-trip can write packed b32 pairs (PV is key-permutation
// invariant as long as P cols and Vt cols share the order).
// ---------------------------------------------------------------------------
__global__ __launch_bounds__(256) void normrope_vt_kernel(
    unsigned short* __restrict__ qkv,
    const float* __restrict__ cosb, const float* __restrict__ sinb,
    const float* __restrict__ qw, const float* __restrict__ kw,
    unsigned short* __restrict__ vtb) {
  const int bid = blockIdx.x;
  const int tid = threadIdx.x;
  if (bid < 10240) {
    const int lane = tid & 63, wave = tid >> 6;
    const int idx = bid * 4 + wave;          // 0..40959 (row id)
    const int h = idx % 5;
    const int bs = idx / 5;
    const int s = bs & (S_LEN - 1);
    unsigned short* base = qkv + (size_t)bs * QKV_N;
    unsigned short* row; const float* w; float oscale;
    if (h < 4) { row = base + h * HD;  w = qw; oscale = ATT_SCALE; }
    else       { row = base + 4 * HD;  w = kw; oscale = 1.0f; }
    // lane handles elements [4*lane, 4*lane+4) = rope pairs pi=2*lane, 2*lane+1
    const uint2 pv = *(const uint2*)(row + 4 * lane);
    float xv[4];
    xv[0] = bf2f((unsigned short)(pv.x & 0xffff));
    xv[1] = bf2f((unsigned short)(pv.x >> 16));
    xv[2] = bf2f((unsigned short)(pv.y & 0xffff));
    xv[3] = bf2f((unsigned short)(pv.y >> 16));
    float ssq = xv[0] * xv[0] + xv[1] * xv[1] + xv[2] * xv[2] + xv[3] * xv[3];
#pragma unroll
    for (int off = 32; off > 0; off >>= 1) ssq += __shfl_xor(ssq, off);
    const float inv = rsqrtf(ssq * (1.0f / 256.0f) + 1e-6f);
    const float4 wv = *(const float4*)(w + 4 * lane);
    const float2 cv = *(const float2*)(cosb + (size_t)s * (HD / 2) + 2 * lane);
    const float2 sv = *(const float2*)(sinb + (size_t)s * (HD / 2) + 2 * lane);
    const float a0 = xv[0] * inv * (1.0f + wv.x);
    const float b0 = xv[1] * inv * (1.0f + wv.y);
    const float a1 = xv[2] * inv * (1.0f + wv.z);
    const float b1 = xv[3] * inv * (1.0f + wv.w);
    const float o0 = (a0 * cv.x - b0 * sv.x) * oscale;
    const float o1 = (a0 * sv.x + b0 * cv.x) * oscale;
    const float o2 = (a1 * cv.y - b1 * sv.y) * oscale;
    const float o3 = (a1 * sv.y + b1 * cv.y) * oscale;
    uint2 ov;
    ov.x = (unsigned int)f2bf(o0) | ((unsigned int)f2bf(o1) << 16);
    ov.y = (unsigned int)f2bf(o2) | ((unsigned int)f2bf(o3) << 16);
    *(uint2*)(row + 4 * lane) = ov;
  } else {
    __shared__ unsigned short ts[32][264];
    const int g2 = bid - 10240;
    const int b = g2 >> 7, jt = g2 & 127;
    const unsigned short* src = qkv + ((size_t)(b * S_LEN) + jt * 32) * QKV_N + 5 * HD;
#pragma unroll
    for (int it = 0; it < 4; ++it) {
      const int c = tid + 256 * it;
      const int row = c >> 5, col8 = (c & 31) << 3;
      *(uint4*)&ts[row][col8] = *(const uint4*)(src + (size_t)row * QKV_N + col8);
    }
    __syncthreads();
    unsigned short tmp[32];
#pragma unroll
    for (int s2 = 0; s2 < 32; ++s2) {
      const int jj = (s2 >> 1) | ((s2 & 1) << 4);   // inverse of s = 2*(jj&15)|(jj>>4)
      tmp[s2] = ts[jj][tid];
    }
    unsigned short* dst = vtb + ((size_t)(b * 128 + jt) * 256 + tid) * 32;
#pragma unroll
    for (int wq = 0; wq < 4; ++wq) *(uint4*)(dst + wq * 8) = *(uint4*)(tmp + wq * 8);
  }
}

// ---------------------------------------------------------------------------
// Flash-style sliding-window MQA, bf16 MFMA — verified R6 structure (88 VGPR,
// 2 blocks/CU) + T5 s_setprio around MFMA clusters (within noise, kept).
// LOCKED: R1 V-direct, R4 key-split, R8/R10 Q-fusion all regressed.
// ---------------------------------------------------------------------------
#define PS_LD 40

__global__ __launch_bounds__(256) void attn_mfma_kernel(
    const unsigned short* __restrict__ qkv, const unsigned short* __restrict__ vtb,
    unsigned short* __restrict__ aob) {
  const int g = blockIdx.x;
  const int xcd = g & 7, slot = g >> 3;      // assume block j -> XCD j%8
  const int h = slot >> 4;                   // 0..3
  const int qt = xcd * 16 + (slot & 15);     // 0..127
  const int b = qt >> 6;
  const int q0 = (qt & 63) << 6;
  const int tid = threadIdx.x;
  const int wave = tid >> 6;
  const int lane = tid & 63;
  const int ln15 = lane & 15;
  const int lgr = lane >> 4;

  __shared__ unsigned short Ks[2][16 * 512];
  __shared__ unsigned short Vts[2][16 * 512];
  __shared__ unsigned short Ps[4][16 * PS_LD];

  const size_t qrow = (size_t)(b * S_LEN + q0 + wave * 16 + ln15) * QKV_N + h * HD;
  s16x8 qfrag[8];
#pragma unroll
  for (int f = 0; f < 8; ++f)
    qfrag[f] = *(const s16x8*)(qkv + qrow + f * 32 + lgr * 8);

  f32x4 acc[16];
#pragma unroll
  for (int t = 0; t < 16; ++t) acc[t] = (f32x4){0.f, 0.f, 0.f, 0.f};
  float l_part[4] = {0.f, 0.f, 0.f, 0.f};

  const int kt_lo = max(0, q0 - WIN) >> 5;
  const int kt_hi = (q0 + 63) >> 5;
  const unsigned short* kbase = qkv + (size_t)(b * S_LEN) * QKV_N + 4 * HD;
  const unsigned short* vbase = vtb + (size_t)b * (S_LEN / 32) * HD * 32;

  auto stage = [&](int kt, int buf) {
#pragma unroll
    for (int u = 0; u < 4; ++u) {
      const int c = wave * 4 + u;
      const int ct = c >> 3, f = c & 7;
      const unsigned short* gk =
          kbase + (size_t)(kt * 32 + ct * 16 + ln15) * QKV_N + f * 32 + lgr * 8;
      gl2lds16(gk, &Ks[buf][c * 512]);
      const unsigned short* gv =
          vbase + (size_t)kt * (HD * 32) + (size_t)(c * 16 + ln15) * 32 + lgr * 8;
      gl2lds16(gv, &Vts[buf][c * 512]);
    }
  };

  stage(kt_lo, 0);
  __syncthreads();

  unsigned short* psw = Ps[wave];
  const int i_row0 = q0 + wave * 16 + lgr * 4;

  for (int kt = kt_lo; kt <= kt_hi; ++kt) {
    const int cur = (kt - kt_lo) & 1;
    if (kt < kt_hi) stage(kt + 1, cur ^ 1);

    // QK^T
    f32x4 sc[2];
    sc[0] = (f32x4){0.f, 0.f, 0.f, 0.f};
    sc[1] = (f32x4){0.f, 0.f, 0.f, 0.f};
    __builtin_amdgcn_s_setprio(1);
#pragma unroll
    for (int f = 0; f < 8; ++f) {
#pragma unroll
      for (int ct = 0; ct < 2; ++ct) {
        const s16x8 kf = *(const s16x8*)&Ks[cur][(ct * 8 + f) * 512 + lane * 8];
        sc[ct] = __builtin_amdgcn_mfma_f32_16x16x32_bf16(qfrag[f], kf, sc[ct], 0, 0, 0);
      }
    }
    __builtin_amdgcn_s_setprio(0);

    // static-max softmax: p = exp(s - 16), masked to 0
    const int j0 = kt * 32 + ln15;
    float p0[4], p1[4];
#pragma unroll
    for (int r = 0; r < 4; ++r) {
      const int i = i_row0 + r;
      const bool a0 = (j0 <= i) && (i - j0 <= WIN);
      const bool a1 = (j0 + 16 <= i) && (i - (j0 + 16) <= WIN);
      const float e0 = __expf(sc[0][r] - 16.0f);
      const float e1 = __expf(sc[1][r] - 16.0f);
      p0[r] = a0 ? e0 : 0.0f;
      p1[r] = a1 ? e1 : 0.0f;
      l_part[r] += p0[r] + p1[r];
    }
    // packed b32 P writes: col 2*ln15 = key ln15 (ct0), col 2*ln15+1 = key 16+ln15
#pragma unroll
    for (int r = 0; r < 4; ++r) {
      const unsigned int pk = (unsigned int)f2bf(p0[r]) | ((unsigned int)f2bf(p1[r]) << 16);
      *(unsigned int*)&psw[(lgr * 4 + r) * PS_LD + (ln15 << 1)] = pk;
    }
    const s16x8 pf = *(const s16x8*)&psw[ln15 * PS_LD + lgr * 8];
    __builtin_amdgcn_s_setprio(1);
#pragma unroll
    for (int t = 0; t < 16; ++t) {
      const s16x8 vf = *(const s16x8*)&Vts[cur][t * 512 + lane * 8];
      acc[t] = __builtin_amdgcn_mfma_f32_16x16x32_bf16(pf, vf, acc[t], 0, 0, 0);
    }
    __builtin_amdgcn_s_setprio(0);
    __syncthreads();
  }

#pragma unroll
  for (int off = 1; off < 16; off <<= 1)
#pragma unroll
    for (int r = 0; r < 4; ++r) l_part[r] += __shfl_xor(l_part[r], off);

  float inv_l[4];
#pragma unroll
  for (int r = 0; r < 4; ++r) inv_l[r] = 1.0f / l_part[r];
#pragma unroll
  for (int t = 0; t < 16; ++t)
#pragma unroll
    for (int r = 0; r < 4; ++r) {
      const size_t orow = (size_t)(b * S_LEN + q0 + wave * 16 + lgr * 4 + r);
      aob[(orow * NH + h) * HD + t * 16 + ln15] = f2bf(acc[t][r] * inv_l[r]);
    }
}

// ---------------------------------------------------------------------------
extern "C" void kernel_launch(void* const* d_in, const int* in_sizes, int n_in,
                              void* d_out, int out_size, void* d_ws, size_t ws_size,
                              hipStream_t stream) {
  const float* x    = (const float*)d_in[0];
  const float* cosb = (const float*)d_in[1];
  const float* sinb = (const float*)d_in[2];
  const float* Wq   = (const float*)d_in[3];
  const float* Wk   = (const float*)d_in[4];
  const float* Wv   = (const float*)d_in[5];
  const float* Wo   = (const float*)d_in[6];
  const float* qw   = (const float*)d_in[7];
  const float* kw   = (const float*)d_in[8];
  float* out = (float*)d_out;

  unsigned short* ws = (unsigned short*)d_ws;
  unsigned short* xb     = ws;                    // 8192*640  = 5242880
  unsigned short* Wqkvt  = xb + 5242880;          // 1536*640  = 983040
  unsigned short* Wot    = Wqkvt + 983040;        // 640*1024  = 655360
  unsigned short* qkvb   = Wot + 655360;          // 8192*1536 = 12582912
  unsigned short* vtb    = qkvb + 12582912;       // 8192*256  = 2097152
  unsigned short* aob    = vtb + 2097152;         // 8192*1024 = 8388608
  const int M = 2 * S_LEN;

  prep_kernel<<<5520, 256, 0, stream>>>(x, xb, Wq, Wk, Wv, Wo, Wqkvt, Wot);
  gemm_bt<true><<<dim3(QKV_N / 128, M / 128), 256, 0, stream>>>(xb, Wqkvt, qkvb, M, QKV_N, 640);
  normrope_vt_kernel<<<10240 + 256, 256, 0, stream>>>(qkvb, cosb, sinb, qw, kw, vtb);
  attn_mfma_kernel<<<M / 64 * NH, 256, 0, stream>>>(qkvb, vtb, aob);
  gemm_bt64<<<dim3(640 / 128, M / 64), 256, 0, stream>>>(aob, Wot, out, M, 640, 1024);
}